// Round 7
// baseline (127.579 us; speedup 1.0000x reference)
//
#include <hip/hip_runtime.h>
#include <hip/hip_bf16.h>
#include <stdint.h>

// Problem dims (fixed by reference)
#define R_TOTAL 1024      // B*S
#define I_DIM   4096
#define OUT_DIM 4096
#define N_STR   32
#define Q_DIM   128

typedef __attribute__((ext_vector_type(8))) __bf16 bf16x8;
typedef __attribute__((ext_vector_type(4))) float  f32x4;

__device__ __forceinline__ ushort f2bf(float f) {
    uint32_t u = __float_as_uint(f);
    uint32_t r = (u + 0x7fffu + ((u >> 16) & 1u)) >> 16;   // RNE
    return (ushort)r;
}

// expand 2 mask bits (2w, 2w+1) -> 32-bit AND-mask for a packed bf16 pair
__device__ __forceinline__ uint32_t bexp(uint32_t b, int w) {
    return ((b >> (2 * w)) & 1u) * 0xFFFFu | ((b >> (2 * w + 1)) & 1u) * 0xFFFF0000u;
}

__device__ __forceinline__ void async16(void* lds, const void* g) {
    __builtin_amdgcn_global_load_lds(
        (const __attribute__((address_space(1))) unsigned int*)g,
        (__attribute__((address_space(3))) unsigned int*)lds, 16, 0, 0);
}

// BK=32 packed-row LDS swizzle: element (r, kbyte) of a [128][64B] tile lives at
//   (r>>1)*128 + ((((r&1)<<6) | kbyte) ^ (((r>>1)&7)<<4))
// Bijective per 128-B packed row (full 7-bit XOR); frag reads (16 consecutive r,
// fixed 16B slot) and staged writes both land <=2-way on banks (free, m136).
__device__ __forceinline__ int swz32(int r, int kbyte) {
    return (r >> 1) * 128 + ((((r & 1) << 6) | kbyte) ^ (((r >> 1) & 7) << 4));
}

// ================= shared device bodies ======================================

// W [I][OUT] f32 -> WT [OUT][I] bf16, one 64x64 tile
__device__ __forceinline__ void transpose_w_block(const float* __restrict__ W,
                                                  ushort* __restrict__ WT,
                                                  int c0, int i0, int t,
                                                  float (*tile)[65]) {
    {
        int dc4 = (t & 15) * 4;
        int di  = t >> 4;
        #pragma unroll
        for (int p = 0; p < 4; ++p) {
            int ii = di + p * 16;
            float4 v = *(const float4*)(W + (size_t)(i0 + ii) * OUT_DIM + c0 + dc4);
            tile[ii][dc4 + 0] = v.x; tile[ii][dc4 + 1] = v.y;
            tile[ii][dc4 + 2] = v.z; tile[ii][dc4 + 3] = v.w;
        }
    }
    __syncthreads();
    {
        int iq = (t & 15) * 4;
        int dc = t >> 4;
        #pragma unroll
        for (int p = 0; p < 4; ++p) {
            int cc = dc + p * 16;
            ushort4 o;
            o.x = f2bf(tile[iq + 0][cc]);
            o.y = f2bf(tile[iq + 1][cc]);
            o.z = f2bf(tile[iq + 2][cc]);
            o.w = f2bf(tile[iq + 3][cc]);
            *(ushort4*)(WT + (size_t)(c0 + cc) * I_DIM + i0 + iq) = o;
        }
    }
}

// XB = bf16(x-mu) + per-stripe bitmasks, one (rb, ib) block of 8 rows x 256 i
__device__ __forceinline__ void prep_block2(const float* __restrict__ x,
                                            const float* __restrict__ mu,
                                            const float* __restrict__ th,
                                            ushort* __restrict__ XB,
                                            unsigned long long* __restrict__ MB64,
                                            int rb, int ib, int tid,
                                            char* smem) {
    ushort* sXB = (ushort*)smem;                                  // 4 KB
    unsigned long long* sMB = (unsigned long long*)(smem + 4096); // 8 KB
    int i = ib * 256 + tid;
    int lane = tid & 63;
    int wave = tid >> 6;

    float muv = mu[i];
    float ax[8];
    #pragma unroll
    for (int rr = 0; rr < 8; ++rr) {
        int r = rb * 8 + rr;
        float xo = x[(size_t)r * I_DIM + i] - muv;
        sXB[rr * 256 + tid] = f2bf(xo);
        ax[rr] = fabsf(xo);
    }
    for (int n4 = 0; n4 < 8; ++n4) {
        float4 tv = *(const float4*)(th + (size_t)i * N_STR + n4 * 4);
        #pragma unroll
        for (int j = 0; j < 4; ++j) {
            float t = (j == 0) ? tv.x : (j == 1) ? tv.y : (j == 2) ? tv.z : tv.w;
            int n = n4 * 4 + j;
            #pragma unroll
            for (int rr = 0; rr < 8; ++rr) {
                unsigned long long bal = __ballot(ax[rr] >= t);
                if (lane == 0) sMB[(n * 8 + rr) * 4 + wave] = bal;
            }
        }
    }
    __syncthreads();
    // coalesced XB write: thread -> (row, 16B segment)
    {
        int row = tid >> 5, seg = tid & 31;
        uint4 v = *(const uint4*)&sXB[row * 256 + seg * 8];
        *(uint4*)(XB + (size_t)(rb * 8 + row) * I_DIM + ib * 256 + seg * 8) = v;
    }
    // coalesced mask write: thread -> (n, rr), 32 contiguous bytes
    {
        int n = tid >> 3, rr = tid & 7;
        const uint4* s = (const uint4*)&sMB[(n * 8 + rr) * 4];
        uint4* dst = (uint4*)((char*)MB64 + ((size_t)n * R_TOTAL + rb * 8 + rr) * 512 + ib * 32);
        dst[0] = s[0];
        dst[1] = s[1];
    }
}

// ---------------- merged pre-pass: transpose_w (0..4095) + prep (4096..6143) -
__global__ __launch_bounds__(256) void k_prep3(const float* __restrict__ W,
                                               ushort* __restrict__ WT,
                                               const float* __restrict__ x,
                                               const float* __restrict__ mu,
                                               const float* __restrict__ th,
                                               ushort* __restrict__ XB,
                                               unsigned long long* __restrict__ MB64) {
    __shared__ __align__(16) float smem[64 * 65];   // 16.25 KB, reused by both
    int b = blockIdx.x;
    int t = threadIdx.x;
    if (b < 4096) {
        transpose_w_block(W, WT, (b & 63) * 64, (b >> 6) * 64, t,
                          (float (*)[65])smem);
    } else {
        b -= 4096;                      // 0..2047
        prep_block2(x, mu, th, XB, MB64, b >> 4, b & 15, t, (char*)smem);
    }
}

// ---------------- standalone pre-passes (fallback path) ----------------------
__global__ __launch_bounds__(256) void k_transpose_th(const float* __restrict__ th,
                                                      float* __restrict__ thT) {
    int idx = blockIdx.x * 256 + threadIdx.x;
    int n = idx >> 12;
    int i = idx & 4095;
    thT[idx] = th[i * N_STR + n];
}

__global__ __launch_bounds__(256) void k_transpose_w(const float* __restrict__ W,
                                                     ushort* __restrict__ WT) {
    __shared__ float tile[64][65];
    transpose_w_block(W, WT, blockIdx.x * 64, blockIdx.y * 64, threadIdx.x, tile);
}

__global__ __launch_bounds__(256) void k_prep2(const float* __restrict__ x,
                                               const float* __restrict__ mu,
                                               const float* __restrict__ th,
                                               ushort* __restrict__ XB,
                                               unsigned long long* __restrict__ MB64) {
    __shared__ __align__(16) char smem[12288];
    prep_block2(x, mu, th, XB, MB64, blockIdx.x >> 4, blockIdx.x & 15,
                threadIdx.x, smem);
}

// ---------------- main v7: occupancy-first. 4 blocks/CU, split-K=4 -----------
// tile 128x128, 4 waves of 64x64, BK=32, dbuf LDS 32 KB, grid 1024,
// __launch_bounds__(256,4) caps VGPR at 128 -> 16 waves/CU (50% occ).
// kq-major XCD map: per-XCD working set B 4MB + XB 2MB (was 12MB).
#define NT7 32   // K-steps of 32 (K=1024 per block)

__global__ __launch_bounds__(256, 4) void k_main7(const ushort* __restrict__ XB,
                                                  const ushort* __restrict__ WT,
                                                  const uint8_t* __restrict__ MB,
                                                  float* __restrict__ P0,
                                                  float* __restrict__ P1,
                                                  float* __restrict__ P2,
                                                  float* __restrict__ P3) {
    __shared__ ushort sA[2][128 * 32];   // 8 KB each
    __shared__ ushort sB[2][128 * 32];   // 8 KB each  (total 32 KB)

    int bid  = blockIdx.x;               // 0..1023
    int xcd  = bid & 7;
    int slot = bid >> 3;                 // 0..127
    int kq   = xcd >> 1;                 // 0..3  (K-quarter, XCD-local)
    int n    = (xcd & 1) * 16 + (slot & 15);   // stripe
    int rt   = (slot >> 4) & 7;          // row tile
    int r0   = rt * 128;
    int k0   = kq * 1024;                // element offset in K
    int cbase = n * Q_DIM;
    float* P = (kq == 0) ? P0 : (kq == 1) ? P1 : (kq == 2) ? P2 : P3;

    int tid  = threadIdx.x;
    int lane = tid & 63;
    int wave = tid >> 6;                 // 0..3
    int wr   = wave >> 1;                // 0..1 : 64-row group
    int wc   = wave & 1;                 // 0..1 : 64-col group
    int lrow = lane & 15;
    int lgrp = lane >> 4;

    // ---- A staging map: pass p in {0,1}: row = p*64 + (tid>>2), 8 elems at (tid&3)*8
    int arow_  = tid >> 2;               // 0..63
    int akslot = tid & 3;
    const ushort*  pXA = XB + (size_t)(r0 + arow_) * I_DIM + k0 + akslot * 8;
    const uint8_t* pMA = MB + ((size_t)n * R_TOTAL + r0 + arow_) * 512 + (k0 >> 3) + akslot;
    int aw[2];
    #pragma unroll
    for (int p = 0; p < 2; ++p)
        aw[p] = swz32(p * 64 + arow_, akslot * 16);

    // ---- B staging map: 2 async16/thread; linear LDS dest, inverse-swz source
    // linear slot (chunk,lane): packed row pr = chunk*8+(lane>>3), off7=((lane&7)^(lane>>3))<<4
    // holds element col = 2*pr + (off7>>6), kbyte = off7&63.
    const char* pBq[2];
    int ldsBo[2];
    #pragma unroll
    for (int q = 0; q < 2; ++q) {
        int chunk = wave * 2 + q;
        int pr    = chunk * 8 + (lane >> 3);
        int v     = (lane & 7) ^ (lane >> 3);
        int col   = 2 * pr + (v >> 2);
        int kbyte = (v & 3) << 4;
        pBq[q] = (const char*)WT + ((size_t)(cbase + col) * I_DIM + k0) * 2 + kbyte;
        ldsBo[q] = chunk * 1024;
    }

    f32x4 acc[4][4];
    #pragma unroll
    for (int m2 = 0; m2 < 4; ++m2)
        #pragma unroll
        for (int nn = 0; nn < 4; ++nn)
            acc[m2][nn] = (f32x4){0.f, 0.f, 0.f, 0.f};

    uint4 va[2]; uint32_t mk[2];

    // ---- prologue: A0 regs, B0 DMA, A0 write, A1 regs, barrier
    #pragma unroll
    for (int p = 0; p < 2; ++p) {
        va[p] = *(const uint4*)(pXA + (size_t)p * 64 * I_DIM);
        mk[p] = *(pMA + (size_t)p * 64 * 512);
    }
    #pragma unroll
    for (int q = 0; q < 2; ++q) async16((char*)sB[0] + ldsBo[q], pBq[q]);
    #pragma unroll
    for (int p = 0; p < 2; ++p) {
        uint4 z;
        z.x = va[p].x & bexp(mk[p], 0); z.y = va[p].y & bexp(mk[p], 1);
        z.z = va[p].z & bexp(mk[p], 2); z.w = va[p].w & bexp(mk[p], 3);
        *(uint4*)((char*)sA[0] + aw[p]) = z;
    }
    #pragma unroll
    for (int p = 0; p < 2; ++p) {
        va[p] = *(const uint4*)(pXA + (size_t)p * 64 * I_DIM + 32);
        mk[p] = *(pMA + (size_t)p * 64 * 512 + 4);
    }
    __syncthreads();

    for (int kt = 0; kt < NT7; ++kt) {
        int cur = kt & 1;
        int nxt = cur ^ 1;
        bool pf = (kt + 1) < NT7;
        if (pf) {
            // B(kt+1) DMA into nxt; A(kt+1) transform+write (va already resident)
            #pragma unroll
            for (int q = 0; q < 2; ++q)
                async16((char*)sB[nxt] + ldsBo[q], pBq[q] + (size_t)(kt + 1) * 64);
            #pragma unroll
            for (int p = 0; p < 2; ++p) {
                uint4 z;
                z.x = va[p].x & bexp(mk[p], 0); z.y = va[p].y & bexp(mk[p], 1);
                z.z = va[p].z & bexp(mk[p], 2); z.w = va[p].w & bexp(mk[p], 3);
                *(uint4*)((char*)sA[nxt] + aw[p]) = z;
            }
            // prefetch A(kt+2) regs (wrapped at tail; harmless re-read)
            int tw = (kt + 2 < NT7) ? (kt + 2) : 0;
            #pragma unroll
            for (int p = 0; p < 2; ++p) {
                va[p] = *(const uint4*)(pXA + (size_t)p * 64 * I_DIM + tw * 32);
                mk[p] = *(pMA + (size_t)p * 64 * 512 + tw * 4);
            }
        }
        // ---- compute tile kt: 16 MFMA, 8 swizzled b128 frag reads
        const char* sAc = (const char*)sA[cur];
        const char* sBc = (const char*)sB[cur];
        int kb = lgrp << 4;
        __builtin_amdgcn_s_setprio(1);
        {
            bf16x8 af[4], bfr[4];
            #pragma unroll
            for (int m2 = 0; m2 < 4; ++m2) {
                int row = wr * 64 + m2 * 16 + lrow;
                af[m2] = *(const bf16x8*)(sAc + swz32(row, kb));
            }
            #pragma unroll
            for (int nn = 0; nn < 4; ++nn) {
                int col = wc * 64 + nn * 16 + lrow;
                bfr[nn] = *(const bf16x8*)(sBc + swz32(col, kb));
            }
            #pragma unroll
            for (int m2 = 0; m2 < 4; ++m2)
                #pragma unroll
                for (int nn = 0; nn < 4; ++nn)
                    acc[m2][nn] = __builtin_amdgcn_mfma_f32_16x16x32_bf16(af[m2], bfr[nn], acc[m2][nn], 0, 0, 0);
        }
        __builtin_amdgcn_s_setprio(0);
        __syncthreads();
    }

    // ---- epilogue: raw f32 partials (out_mu added in k_reduce4)
    #pragma unroll
    for (int nn = 0; nn < 4; ++nn) {
        int col = cbase + wc * 64 + nn * 16 + lrow;
        #pragma unroll
        for (int m2 = 0; m2 < 4; ++m2) {
            int rbase = r0 + wr * 64 + m2 * 16 + lgrp * 4;
            #pragma unroll
            for (int j = 0; j < 4; ++j)
                P[(size_t)(rbase + j) * OUT_DIM + col] = acc[m2][nn][j];
        }
    }
}

// ---------------- reduce: out = P0(out) + P1 + P2 + P3 + out_mu --------------
__global__ __launch_bounds__(256) void k_reduce4(float* __restrict__ out,
                                                 const float* __restrict__ P1,
                                                 const float* __restrict__ P2,
                                                 const float* __restrict__ P3,
                                                 const float* __restrict__ out_mu) {
    int idx = blockIdx.x * 256 + threadIdx.x;       // float4 index, 1M total
    float4 a = ((const float4*)out)[idx];
    float4 b = ((const float4*)P1)[idx];
    float4 c = ((const float4*)P2)[idx];
    float4 d = ((const float4*)P3)[idx];
    float4 m = ((const float4*)out_mu)[idx & 1023];
    a.x += b.x + c.x + d.x + m.x;
    a.y += b.y + c.y + d.y + m.y;
    a.z += b.z + c.z + d.z + m.z;
    a.w += b.w + c.w + d.w + m.w;
    ((float4*)out)[idx] = a;
}

// ---------------- reduce (split-K=2 fallback): out = P0 + P1 + out_mu --------
__global__ __launch_bounds__(256) void k_reduce(float* __restrict__ out,
                                                const float* __restrict__ P1,
                                                const float* __restrict__ out_mu) {
    int idx = blockIdx.x * 256 + threadIdx.x;
    float4 a = ((const float4*)out)[idx];
    float4 b = ((const float4*)P1)[idx];
    float4 m = ((const float4*)out_mu)[idx & 1023];
    a.x += b.x + m.x; a.y += b.y + m.y; a.z += b.z + m.z; a.w += b.w + m.w;
    ((float4*)out)[idx] = a;
}

// ---------------- fallback main v5 (R5: split-K=2, tri-buf) ------------------
#define NT5 32

__global__ __launch_bounds__(256, 2) void k_main5(const ushort* __restrict__ XB,
                                                  const ushort* __restrict__ WT,
                                                  const uint8_t* __restrict__ MB,
                                                  float* __restrict__ P0,
                                                  float* __restrict__ P1) {
    __shared__ ushort sA[2][128 * 64];
    __shared__ ushort sB[3][128 * 64];

    int bid  = blockIdx.x;
    int xcd  = bid & 7;
    int slot = bid >> 3;
    int n    = xcd * 4 + (slot & 3);
    int rt   = (slot >> 2) & 7;
    int kh   = slot >> 5;
    int r0   = rt * 128;
    int k0   = kh * 2048;
    int cbase = n * Q_DIM;
    float* P = kh ? P1 : P0;

    int tid  = threadIdx.x;
    int lane = tid & 63;
    int wave = tid >> 6;
    int wr   = wave >> 1;
    int wc   = wave & 1;
    int lrow = lane & 15;
    int lgrp = lane >> 4;

    const ushort*  pXA[4];
    const uint8_t* pMA[4];
    int awz[4];
    {
        int ar = tid >> 3;
        int ak = (tid & 7) * 8;
        #pragma unroll
        for (int p = 0; p < 4; ++p) {
            int row = p * 32 + ar;
            pXA[p] = XB + (size_t)(r0 + row) * I_DIM + k0 + ak;
            pMA[p] = MB + ((size_t)n * R_TOTAL + r0 + row) * 512 + (k0 >> 3) + (tid & 7);
            awz[p] = row * 128 + ((ak * 2) ^ ((row & 7) << 4));
        }
    }
    const char* pBq[4];
    int ldsBo[4];
    #pragma unroll
    for (int q = 0; q < 4; ++q) {
        int chunk = wave * 4 + q;
        int col = chunk * 8 + (lane >> 3);
        pBq[q] = (const char*)WT + (size_t)(cbase + col) * (I_DIM * 2)
               + (size_t)k0 * 2 + (((lane & 7) ^ (lane >> 3)) << 4);
        ldsBo[q] = chunk * 1024;
    }

    f32x4 acc[4][4];
    #pragma unroll
    for (int m2 = 0; m2 < 4; ++m2)
        #pragma unroll
        for (int nn = 0; nn < 4; ++nn)
            acc[m2][nn] = (f32x4){0.f, 0.f, 0.f, 0.f};

    uint4 va[4]; uint32_t mk[4];
    {
        #pragma unroll
        for (int q = 0; q < 4; ++q) { async16((char*)sB[0] + ldsBo[q], pBq[q]); pBq[q] += 128; }
        #pragma unroll
        for (int q = 0; q < 4; ++q) { async16((char*)sB[1] + ldsBo[q], pBq[q]); pBq[q] += 128; }
        #pragma unroll
        for (int p = 0; p < 4; ++p) { va[p] = *(const uint4*)pXA[p]; mk[p] = *pMA[p];
                                      pXA[p] += 64; pMA[p] += 8; }
        #pragma unroll
        for (int p = 0; p < 4; ++p) {
            uint4 z;
            z.x = va[p].x & bexp(mk[p], 0); z.y = va[p].y & bexp(mk[p], 1);
            z.z = va[p].z & bexp(mk[p], 2); z.w = va[p].w & bexp(mk[p], 3);
            *(uint4*)((char*)sA[0] + awz[p]) = z;
        }
        #pragma unroll
        for (int p = 0; p < 4; ++p) { va[p] = *(const uint4*)pXA[p]; mk[p] = *pMA[p];
                                      pXA[p] += 64; pMA[p] += 8; }
        asm volatile("s_waitcnt lgkmcnt(0)" ::: "memory");
        __builtin_amdgcn_s_barrier();
    }
    for (int t = 0; t < NT5; ++t) {
        if (t + 2 < NT5) {
            int buf = (t + 2) % 3;
            #pragma unroll
            for (int q = 0; q < 4; ++q) {
                async16((char*)sB[buf] + ldsBo[q], pBq[q]);
                pBq[q] += 128;
            }
        }
        const char* sAc = (const char*)sA[t & 1];
        const char* sBc = (const char*)sB[t % 3];
        __builtin_amdgcn_s_setprio(1);
        #pragma unroll
        for (int ks = 0; ks < 2; ++ks) {
            int kb = ks * 64 + (lgrp << 4);
            bf16x8 af[4], bfr[4];
            #pragma unroll
            for (int m2 = 0; m2 < 4; ++m2) {
                int row = wr * 64 + m2 * 16 + lrow;
                af[m2] = *(const bf16x8*)(sAc + row * 128 + (kb ^ ((row & 7) << 4)));
            }
            #pragma unroll
            for (int nn = 0; nn < 4; ++nn) {
                int col = wc * 64 + nn * 16 + lrow;
                bfr[nn] = *(const bf16x8*)(sBc + col * 128 + (kb ^ ((col & 7) << 4)));
            }
            #pragma unroll
            for (int m2 = 0; m2 < 4; ++m2)
                #pragma unroll
                for (int nn = 0; nn < 4; ++nn)
                    acc[m2][nn] = __builtin_amdgcn_mfma_f32_16x16x32_bf16(af[m2], bfr[nn], acc[m2][nn], 0, 0, 0);
        }
        __builtin_amdgcn_s_setprio(0);
        if (t + 1 < NT5) {
            #pragma unroll
            for (int p = 0; p < 4; ++p) {
                uint4 z;
                z.x = va[p].x & bexp(mk[p], 0); z.y = va[p].y & bexp(mk[p], 1);
                z.z = va[p].z & bexp(mk[p], 2); z.w = va[p].w & bexp(mk[p], 3);
                *(uint4*)((char*)sA[(t + 1) & 1] + awz[p]) = z;
            }
        }
        asm volatile("s_waitcnt vmcnt(4)" ::: "memory");
        if (t + 2 < NT5) {
            #pragma unroll
            for (int p = 0; p < 4; ++p) { va[p] = *(const uint4*)pXA[p]; mk[p] = *pMA[p];
                                          pXA[p] += 64; pMA[p] += 8; }
        }
        asm volatile("s_waitcnt lgkmcnt(0)" ::: "memory");
        __builtin_amdgcn_s_barrier();
    }
    #pragma unroll
    for (int nn = 0; nn < 4; ++nn) {
        int col = cbase + wc * 64 + nn * 16 + lrow;
        #pragma unroll
        for (int m2 = 0; m2 < 4; ++m2) {
            int rbase = r0 + wr * 64 + m2 * 16 + lgrp * 4;
            #pragma unroll
            for (int j = 0; j < 4; ++j)
                P[(size_t)(rbase + j) * OUT_DIM + col] = acc[m2][nn][j];
        }
    }
}

// ---------------- fallback main v1 (reg-staged from fp32 x) ------------------
#define BM 128
#define BN 128
#define BK 64
__global__ __launch_bounds__(512) void k_main1(const float* __restrict__ x,
                                               const ushort* __restrict__ WT,
                                               const float* __restrict__ thT,
                                               const float* __restrict__ mu,
                                               const float* __restrict__ out_mu,
                                               float* __restrict__ out) {
    int bid  = blockIdx.x;
    int xcd  = bid & 7;
    int slot = bid >> 3;
    int n    = xcd * 4 + (slot >> 3);
    int mt   = slot & 7;
    int r0   = mt * BM;
    int cbase = n * Q_DIM;

    __shared__ ushort sA[BM * BK];
    __shared__ ushort sB[BN * BK];

    int tid  = threadIdx.x;
    int lane = tid & 63;
    int wave = tid >> 6;
    int wr   = wave >> 2;
    int wc   = wave & 3;

    f32x4 acc[4][2];
    #pragma unroll
    for (int m2 = 0; m2 < 4; ++m2)
        #pragma unroll
        for (int nn = 0; nn < 2; ++nn)
            acc[m2][nn] = (f32x4){0.f, 0.f, 0.f, 0.f};

    const int a_kq  = (tid & 15) * 4;
    const int a_rb  = tid >> 4;
    const int b_ko  = (tid & 7) * 8;
    const int b_cb  = tid >> 3;
    const int lrow  = lane & 15;
    const int lgrp  = lane >> 4;

    for (int kt = 0; kt < I_DIM / BK; ++kt) {
        int k0 = kt * BK;
        float4 thv = *(const float4*)(thT + (size_t)n * I_DIM + k0 + a_kq);
        float4 muv = *(const float4*)(mu + k0 + a_kq);
        #pragma unroll
        for (int p = 0; p < 4; ++p) {
            int row = a_rb + p * 32;
            float4 xv = *(const float4*)(x + (size_t)(r0 + row) * I_DIM + k0 + a_kq);
            float v0 = xv.x - muv.x, v1 = xv.y - muv.y, v2 = xv.z - muv.z, v3 = xv.w - muv.w;
            v0 = (fabsf(v0) >= thv.x) ? v0 : 0.f;
            v1 = (fabsf(v1) >= thv.y) ? v1 : 0.f;
            v2 = (fabsf(v2) >= thv.z) ? v2 : 0.f;
            v3 = (fabsf(v3) >= thv.w) ? v3 : 0.f;
            uint2 pk;
            pk.x = (uint32_t)f2bf(v0) | ((uint32_t)f2bf(v1) << 16);
            pk.y = (uint32_t)f2bf(v2) | ((uint32_t)f2bf(v3) << 16);
            int kbyte = (a_kq * 2) ^ ((row & 7) << 4);
            *(uint2*)((char*)sA + row * (BK * 2) + kbyte) = pk;
        }
        #pragma unroll
        for (int p = 0; p < 2; ++p) {
            int col = b_cb + p * 64;
            uint4 wv = *(const uint4*)(WT + (size_t)(cbase + col) * I_DIM + k0 + b_ko);
            int kbyte = (b_ko * 2) ^ ((col & 7) << 4);
            *(uint4*)((char*)sB + col * (BK * 2) + kbyte) = wv;
        }
        __syncthreads();
        #pragma unroll
        for (int ks = 0; ks < 2; ++ks) {
            int kb = ks * 64 + (lgrp << 4);
            bf16x8 af[4], bfr[2];
            #pragma unroll
            for (int m2 = 0; m2 < 4; ++m2) {
                int row = wr * 64 + m2 * 16 + lrow;
                af[m2] = *(const bf16x8*)((const char*)sA + row * (BK * 2) + (kb ^ ((row & 7) << 4)));
            }
            #pragma unroll
            for (int nn = 0; nn < 2; ++nn) {
                int col = wc * 32 + nn * 16 + lrow;
                bfr[nn] = *(const bf16x8*)((const char*)sB + col * (BK * 2) + (kb ^ ((col & 7) << 4)));
            }
            #pragma unroll
            for (int m2 = 0; m2 < 4; ++m2)
                #pragma unroll
                for (int nn = 0; nn < 2; ++nn)
                    acc[m2][nn] = __builtin_amdgcn_mfma_f32_16x16x32_bf16(af[m2], bfr[nn], acc[m2][nn], 0, 0, 0);
        }
        __syncthreads();
    }

    #pragma unroll
    for (int nn = 0; nn < 2; ++nn) {
        int col = cbase + wc * 32 + nn * 16 + lrow;
        float om = out_mu[col];
        #pragma unroll
        for (int m2 = 0; m2 < 4; ++m2) {
            int rbase = r0 + wr * 64 + m2 * 16 + lgrp * 4;
            #pragma unroll
            for (int j = 0; j < 4; ++j)
                out[(size_t)(rbase + j) * OUT_DIM + col] = acc[m2][nn][j] + om;
        }
    }
}

// ---------------- fallback: naive fp32 ---------------------------------------
__global__ __launch_bounds__(256) void k_naive(const float* __restrict__ x,
                                               const float* __restrict__ W,
                                               const float* __restrict__ th,
                                               const float* __restrict__ mu,
                                               const float* __restrict__ out_mu,
                                               float* __restrict__ out) {
    int idx = blockIdx.x * 256 + threadIdx.x;
    int r = idx >> 12;
    int c = idx & 4095;
    int n = c >> 7;
    float s = 0.f;
    for (int i = 0; i < I_DIM; ++i) {
        float xo = x[(size_t)r * I_DIM + i] - mu[i];
        if (fabsf(xo) >= th[i * N_STR + n])
            s += xo * W[(size_t)i * OUT_DIM + c];
    }
    out[idx] = s + out_mu[c];
}

extern "C" void kernel_launch(void* const* d_in, const int* in_sizes, int n_in,
                              void* d_out, int out_size, void* d_ws, size_t ws_size,
                              hipStream_t stream) {
    const float* x      = (const float*)d_in[0];
    const float* W      = (const float*)d_in[1];
    const float* th     = (const float*)d_in[2];
    const float* mu     = (const float*)d_in[3];
    const float* out_mu = (const float*)d_in[4];
    float* out = (float*)d_out;

    const size_t thT_b = (size_t)N_STR * I_DIM * sizeof(float);      // 0.5 MiB
    const size_t wT_b  = (size_t)OUT_DIM * I_DIM * sizeof(ushort);   // 32 MiB
    const size_t xb_b  = (size_t)R_TOTAL * I_DIM * sizeof(ushort);   // 8 MiB
    const size_t mb_b  = (size_t)N_STR * R_TOTAL * 512;              // 16 MiB
    const size_t p_b   = (size_t)R_TOTAL * OUT_DIM * sizeof(float);  // 16 MiB each

    ushort*  WT  = (ushort*)((char*)d_ws + thT_b);
    ushort*  XBp = (ushort*)((char*)d_ws + thT_b + wT_b);
    uint8_t* MBp = (uint8_t*)((char*)d_ws + thT_b + wT_b + xb_b);
    float*   P1  = (float*)((char*)d_ws + thT_b + wT_b + xb_b + mb_b);
    float*   P2  = (float*)((char*)d_ws + thT_b + wT_b + xb_b + mb_b + p_b);
    float*   P3  = (float*)((char*)d_ws + thT_b + wT_b + xb_b + mb_b + 2 * p_b);

    if (ws_size >= thT_b + wT_b + xb_b + mb_b + 3 * p_b) {
        // fast path: merged pre-pass, split-K=4 occupancy-first main, reduce
        k_prep3<<<4096 + 2048, 256, 0, stream>>>(W, WT, x, mu, th, XBp,
                                                 (unsigned long long*)MBp);
        k_main7<<<1024, 256, 0, stream>>>(XBp, WT, MBp, out, P1, P2, P3);
        k_reduce4<<<(R_TOTAL * OUT_DIM / 4) / 256, 256, 0, stream>>>(out, P1, P2, P3, out_mu);
    } else if (ws_size >= thT_b + wT_b + xb_b + mb_b + p_b) {
        k_prep3<<<4096 + 2048, 256, 0, stream>>>(W, WT, x, mu, th, XBp,
                                                 (unsigned long long*)MBp);
        k_main5<<<512, 256, 0, stream>>>(XBp, WT, MBp, out, P1);
        k_reduce<<<(R_TOTAL * OUT_DIM / 4) / 256, 256, 0, stream>>>(out, P1, out_mu);
    } else if (ws_size >= thT_b + wT_b) {
        float* thT = (float*)d_ws;
        k_transpose_th<<<(N_STR * I_DIM) / 256, 256, 0, stream>>>(th, thT);
        k_transpose_w<<<dim3(OUT_DIM / 64, I_DIM / 64), 256, 0, stream>>>(W, WT);
        k_main1<<<256, 512, 0, stream>>>(x, WT, thT, mu, out_mu, out);
    } else {
        k_naive<<<(R_TOTAL * OUT_DIM) / 256, 256, 0, stream>>>(x, W, th, mu, out_mu, out);
    }
}

// Round 8
// 109.722 us; speedup vs baseline: 1.1627x; 1.1627x over previous
//
#include <hip/hip_runtime.h>
#include <hip/hip_bf16.h>
#include <stdint.h>

// Problem dims (fixed by reference)
#define R_TOTAL 1024      // B*S
#define I_DIM   4096
#define OUT_DIM 4096
#define N_STR   32
#define Q_DIM   128

typedef __attribute__((ext_vector_type(8))) __bf16 bf16x8;
typedef __attribute__((ext_vector_type(4))) float  f32x4;

__device__ __forceinline__ ushort f2bf(float f) {
    uint32_t u = __float_as_uint(f);
    uint32_t r = (u + 0x7fffu + ((u >> 16) & 1u)) >> 16;   // RNE
    return (ushort)r;
}

// expand 2 mask bits (2w, 2w+1) -> 32-bit AND-mask for a packed bf16 pair
__device__ __forceinline__ uint32_t bexp(uint32_t b, int w) {
    return ((b >> (2 * w)) & 1u) * 0xFFFFu | ((b >> (2 * w + 1)) & 1u) * 0xFFFF0000u;
}

__device__ __forceinline__ void async16(void* lds, const void* g) {
    __builtin_amdgcn_global_load_lds(
        (const __attribute__((address_space(1))) unsigned int*)g,
        (__attribute__((address_space(3))) unsigned int*)lds, 16, 0, 0);
}

// ================= shared device bodies ======================================

// W [I][OUT] f32 -> WT [OUT][I] bf16, one 64x64 tile
__device__ __forceinline__ void transpose_w_block(const float* __restrict__ W,
                                                  ushort* __restrict__ WT,
                                                  int c0, int i0, int t,
                                                  float (*tile)[65]) {
    {
        int dc4 = (t & 15) * 4;
        int di  = t >> 4;
        #pragma unroll
        for (int p = 0; p < 4; ++p) {
            int ii = di + p * 16;
            float4 v = *(const float4*)(W + (size_t)(i0 + ii) * OUT_DIM + c0 + dc4);
            tile[ii][dc4 + 0] = v.x; tile[ii][dc4 + 1] = v.y;
            tile[ii][dc4 + 2] = v.z; tile[ii][dc4 + 3] = v.w;
        }
    }
    __syncthreads();
    {
        int iq = (t & 15) * 4;
        int dc = t >> 4;
        #pragma unroll
        for (int p = 0; p < 4; ++p) {
            int cc = dc + p * 16;
            ushort4 o;
            o.x = f2bf(tile[iq + 0][cc]);
            o.y = f2bf(tile[iq + 1][cc]);
            o.z = f2bf(tile[iq + 2][cc]);
            o.w = f2bf(tile[iq + 3][cc]);
            *(ushort4*)(WT + (size_t)(c0 + cc) * I_DIM + i0 + iq) = o;
        }
    }
}

// XB = bf16(x-mu) + per-stripe bitmasks, one (rb, ib) block of 8 rows x 256 i
__device__ __forceinline__ void prep_block2(const float* __restrict__ x,
                                            const float* __restrict__ mu,
                                            const float* __restrict__ th,
                                            ushort* __restrict__ XB,
                                            unsigned long long* __restrict__ MB64,
                                            int rb, int ib, int tid,
                                            char* smem) {
    ushort* sXB = (ushort*)smem;                                  // 4 KB
    unsigned long long* sMB = (unsigned long long*)(smem + 4096); // 8 KB
    int i = ib * 256 + tid;
    int lane = tid & 63;
    int wave = tid >> 6;

    float muv = mu[i];
    float ax[8];
    #pragma unroll
    for (int rr = 0; rr < 8; ++rr) {
        int r = rb * 8 + rr;
        float xo = x[(size_t)r * I_DIM + i] - muv;
        sXB[rr * 256 + tid] = f2bf(xo);
        ax[rr] = fabsf(xo);
    }
    for (int n4 = 0; n4 < 8; ++n4) {
        float4 tv = *(const float4*)(th + (size_t)i * N_STR + n4 * 4);
        #pragma unroll
        for (int j = 0; j < 4; ++j) {
            float t = (j == 0) ? tv.x : (j == 1) ? tv.y : (j == 2) ? tv.z : tv.w;
            int n = n4 * 4 + j;
            #pragma unroll
            for (int rr = 0; rr < 8; ++rr) {
                unsigned long long bal = __ballot(ax[rr] >= t);
                if (lane == 0) sMB[(n * 8 + rr) * 4 + wave] = bal;
            }
        }
    }
    __syncthreads();
    // coalesced XB write: thread -> (row, 16B segment)
    {
        int row = tid >> 5, seg = tid & 31;
        uint4 v = *(const uint4*)&sXB[row * 256 + seg * 8];
        *(uint4*)(XB + (size_t)(rb * 8 + row) * I_DIM + ib * 256 + seg * 8) = v;
    }
    // coalesced mask write: thread -> (n, rr), 32 contiguous bytes
    {
        int n = tid >> 3, rr = tid & 7;
        const uint4* s = (const uint4*)&sMB[(n * 8 + rr) * 4];
        uint4* dst = (uint4*)((char*)MB64 + ((size_t)n * R_TOTAL + rb * 8 + rr) * 512 + ib * 32);
        dst[0] = s[0];
        dst[1] = s[1];
    }
}

// ---------------- merged pre-pass: transpose_w (0..4095) + prep (4096..6143) -
__global__ __launch_bounds__(256) void k_prep3(const float* __restrict__ W,
                                               ushort* __restrict__ WT,
                                               const float* __restrict__ x,
                                               const float* __restrict__ mu,
                                               const float* __restrict__ th,
                                               ushort* __restrict__ XB,
                                               unsigned long long* __restrict__ MB64) {
    __shared__ __align__(16) float smem[64 * 65];   // 16.25 KB, reused by both
    int b = blockIdx.x;
    int t = threadIdx.x;
    if (b < 4096) {
        transpose_w_block(W, WT, (b & 63) * 64, (b >> 6) * 64, t,
                          (float (*)[65])smem);
    } else {
        b -= 4096;                      // 0..2047
        prep_block2(x, mu, th, XB, MB64, b >> 4, b & 15, t, (char*)smem);
    }
}

// ---------------- main v8: cross-block hiding. 3 blocks/CU, split-K=3 --------
// tile 128x128, 4 waves of 64x64, BK=64. sA single-buf (16K) + sB dbuf (32K)
// = 48 KB -> 3 blocks/CU (12 waves, 37% occ). B-DMA issued 1 step ahead,
// lands under the 32-MFMA compute phase; __syncthreads drains covered by the
// other 2 resident blocks (m114 MFMA/VALU co-scheduling).
// Split-K=3 uneven: steps 22/21/21 of BK=64 (K = 1408/1344/1344).

__global__ __launch_bounds__(256, 3) void k_main8(const ushort* __restrict__ XB,
                                                  const ushort* __restrict__ WT,
                                                  const uint8_t* __restrict__ MB,
                                                  float* __restrict__ P0,
                                                  float* __restrict__ P1,
                                                  float* __restrict__ P2) {
    __shared__ ushort sA[128 * 64];      // 16 KB (single)
    __shared__ ushort sB[2][128 * 64];   // 16 KB each

    int bid  = blockIdx.x;               // 0..767
    int xcd  = bid & 7;
    int slot = bid >> 3;                 // 0..95
    int n    = xcd * 4 + (slot & 3);     // stripe (XCD-local group of 4)
    int rt   = (slot >> 2) & 7;          // row tile 0..7
    int kq   = slot >> 5;                // 0..2
    int r0   = rt * 128;
    int k0   = (kq == 0) ? 0 : (kq == 1) ? 1408 : 2752;
    int NT   = (kq == 0) ? 22 : 21;
    int cbase = n * Q_DIM;
    float* P = (kq == 0) ? P0 : (kq == 1) ? P1 : P2;

    int tid  = threadIdx.x;
    int lane = tid & 63;
    int wave = tid >> 6;                 // 0..3
    int wr   = wave >> 1;                // 0..1 : 64-row group
    int wc   = wave & 1;                 // 0..1 : 64-col group
    int lrow = lane & 15;
    int lgrp = lane >> 4;

    // ---- A staging maps (R5-proven): pass p: row = p*32 + (tid>>3), 8 elems
    const ushort*  pXA[4];
    const uint8_t* pMA[4];
    int awz[4];
    {
        int ar = tid >> 3;
        int ak = (tid & 7) * 8;
        #pragma unroll
        for (int p = 0; p < 4; ++p) {
            int row = p * 32 + ar;
            pXA[p] = XB + (size_t)(r0 + row) * I_DIM + k0 + ak;
            pMA[p] = MB + ((size_t)n * R_TOTAL + r0 + row) * 512 + (k0 >> 3) + (tid & 7);
            awz[p] = row * 128 + ((ak * 2) ^ ((row & 7) << 4));
        }
    }

    // ---- B staging maps (R5-proven): 16 chunks of 1KB; pre-swizzled source
    const char* pBq[4];
    int ldsBo[4];
    #pragma unroll
    for (int q = 0; q < 4; ++q) {
        int chunk = wave * 4 + q;
        int col = chunk * 8 + (lane >> 3);
        pBq[q] = (const char*)WT + (size_t)(cbase + col) * (I_DIM * 2)
               + (size_t)k0 * 2 + (((lane & 7) ^ (lane >> 3)) << 4);
        ldsBo[q] = chunk * 1024;
    }

    f32x4 acc[4][4];
    #pragma unroll
    for (int m2 = 0; m2 < 4; ++m2)
        #pragma unroll
        for (int nn = 0; nn < 4; ++nn)
            acc[m2][nn] = (f32x4){0.f, 0.f, 0.f, 0.f};

    uint4 va[4]; uint32_t mk[4];

    // ---- prologue: A0 regs; B0 DMA; write sA(0); A1 regs; barrier
    #pragma unroll
    for (int p = 0; p < 4; ++p) { va[p] = *(const uint4*)pXA[p]; mk[p] = *pMA[p]; }
    #pragma unroll
    for (int q = 0; q < 4; ++q) async16((char*)sB[0] + ldsBo[q], pBq[q]);
    #pragma unroll
    for (int p = 0; p < 4; ++p) {
        uint4 z;
        z.x = va[p].x & bexp(mk[p], 0); z.y = va[p].y & bexp(mk[p], 1);
        z.z = va[p].z & bexp(mk[p], 2); z.w = va[p].w & bexp(mk[p], 3);
        *(uint4*)((char*)sA + awz[p]) = z;
    }
    #pragma unroll
    for (int p = 0; p < 4; ++p) { va[p] = *(const uint4*)(pXA[p] + 64); mk[p] = *(pMA[p] + 8); }
    __syncthreads();                     // sA(0), sB[0] ready

    for (int t = 0; t < NT; ++t) {
        // issue B(t+1) DMA into the other sB buffer (lands under compute)
        if (t + 1 < NT) {
            #pragma unroll
            for (int q = 0; q < 4; ++q)
                async16((char*)sB[(t + 1) & 1] + ldsBo[q],
                        pBq[q] + (size_t)(t + 1) * 128);
        }
        // ---- compute tile t (sA single, sB[t&1])
        const char* sAc = (const char*)sA;
        const char* sBc = (const char*)sB[t & 1];
        __builtin_amdgcn_s_setprio(1);
        #pragma unroll
        for (int ks = 0; ks < 2; ++ks) {
            int kb = ks * 64 + (lgrp << 4);
            bf16x8 af[4], bfr[4];
            #pragma unroll
            for (int m2 = 0; m2 < 4; ++m2) {
                int row = wr * 64 + m2 * 16 + lrow;
                af[m2] = *(const bf16x8*)(sAc + row * 128 + (kb ^ ((row & 7) << 4)));
            }
            #pragma unroll
            for (int nn = 0; nn < 4; ++nn) {
                int col = wc * 64 + nn * 16 + lrow;
                bfr[nn] = *(const bf16x8*)(sBc + col * 128 + (kb ^ ((col & 7) << 4)));
            }
            #pragma unroll
            for (int m2 = 0; m2 < 4; ++m2)
                #pragma unroll
                for (int nn = 0; nn < 4; ++nn)
                    acc[m2][nn] = __builtin_amdgcn_mfma_f32_16x16x32_bf16(af[m2], bfr[nn], acc[m2][nn], 0, 0, 0);
        }
        __builtin_amdgcn_s_setprio(0);
        __syncthreads();                 // compute done; B(t+1)+A-regs drained
        // ---- write sA(t+1); prefetch A(t+2) regs
        if (t + 1 < NT) {
            #pragma unroll
            for (int p = 0; p < 4; ++p) {
                uint4 z;
                z.x = va[p].x & bexp(mk[p], 0); z.y = va[p].y & bexp(mk[p], 1);
                z.z = va[p].z & bexp(mk[p], 2); z.w = va[p].w & bexp(mk[p], 3);
                *(uint4*)((char*)sA + awz[p]) = z;
            }
            if (t + 2 < NT) {
                #pragma unroll
                for (int p = 0; p < 4; ++p) {
                    va[p] = *(const uint4*)(pXA[p] + (size_t)(t + 2) * 64);
                    mk[p] = *(pMA[p] + (size_t)(t + 2) * 8);
                }
            }
        }
        __syncthreads();                 // sA(t+1) visible
    }

    // ---- epilogue: raw f32 partials (out_mu added in k_reduce3)
    #pragma unroll
    for (int nn = 0; nn < 4; ++nn) {
        int col = cbase + wc * 64 + nn * 16 + lrow;
        #pragma unroll
        for (int m2 = 0; m2 < 4; ++m2) {
            int rbase = r0 + wr * 64 + m2 * 16 + lgrp * 4;
            #pragma unroll
            for (int j = 0; j < 4; ++j)
                P[(size_t)(rbase + j) * OUT_DIM + col] = acc[m2][nn][j];
        }
    }
}

// ---------------- reduce: out = P0(out) + P1 + P2 + out_mu -------------------
__global__ __launch_bounds__(256) void k_reduce3(float* __restrict__ out,
                                                 const float* __restrict__ P1,
                                                 const float* __restrict__ P2,
                                                 const float* __restrict__ out_mu) {
    int idx = blockIdx.x * 256 + threadIdx.x;       // float4 index, 1M total
    float4 a = ((const float4*)out)[idx];
    float4 b = ((const float4*)P1)[idx];
    float4 c = ((const float4*)P2)[idx];
    float4 m = ((const float4*)out_mu)[idx & 1023];
    a.x += b.x + c.x + m.x;
    a.y += b.y + c.y + m.y;
    a.z += b.z + c.z + m.z;
    a.w += b.w + c.w + m.w;
    ((float4*)out)[idx] = a;
}

// ---------------- reduce (split-K=2 fallback) --------------------------------
__global__ __launch_bounds__(256) void k_reduce(float* __restrict__ out,
                                                const float* __restrict__ P1,
                                                const float* __restrict__ out_mu) {
    int idx = blockIdx.x * 256 + threadIdx.x;
    float4 a = ((const float4*)out)[idx];
    float4 b = ((const float4*)P1)[idx];
    float4 m = ((const float4*)out_mu)[idx & 1023];
    a.x += b.x + m.x; a.y += b.y + m.y; a.z += b.z + m.z; a.w += b.w + m.w;
    ((float4*)out)[idx] = a;
}

// ---------------- fallback main v5 (R5: split-K=2, tri-buf) ------------------
#define NT5 32

__global__ __launch_bounds__(256, 2) void k_main5(const ushort* __restrict__ XB,
                                                  const ushort* __restrict__ WT,
                                                  const uint8_t* __restrict__ MB,
                                                  float* __restrict__ P0,
                                                  float* __restrict__ P1) {
    __shared__ ushort sA[2][128 * 64];
    __shared__ ushort sB[3][128 * 64];

    int bid  = blockIdx.x;
    int xcd  = bid & 7;
    int slot = bid >> 3;
    int n    = xcd * 4 + (slot & 3);
    int rt   = (slot >> 2) & 7;
    int kh   = slot >> 5;
    int r0   = rt * 128;
    int k0   = kh * 2048;
    int cbase = n * Q_DIM;
    float* P = kh ? P1 : P0;

    int tid  = threadIdx.x;
    int lane = tid & 63;
    int wave = tid >> 6;
    int wr   = wave >> 1;
    int wc   = wave & 1;
    int lrow = lane & 15;
    int lgrp = lane >> 4;

    const ushort*  pXA[4];
    const uint8_t* pMA[4];
    int awz[4];
    {
        int ar = tid >> 3;
        int ak = (tid & 7) * 8;
        #pragma unroll
        for (int p = 0; p < 4; ++p) {
            int row = p * 32 + ar;
            pXA[p] = XB + (size_t)(r0 + row) * I_DIM + k0 + ak;
            pMA[p] = MB + ((size_t)n * R_TOTAL + r0 + row) * 512 + (k0 >> 3) + (tid & 7);
            awz[p] = row * 128 + ((ak * 2) ^ ((row & 7) << 4));
        }
    }
    const char* pBq[4];
    int ldsBo[4];
    #pragma unroll
    for (int q = 0; q < 4; ++q) {
        int chunk = wave * 4 + q;
        int col = chunk * 8 + (lane >> 3);
        pBq[q] = (const char*)WT + (size_t)(cbase + col) * (I_DIM * 2)
               + (size_t)k0 * 2 + (((lane & 7) ^ (lane >> 3)) << 4);
        ldsBo[q] = chunk * 1024;
    }

    f32x4 acc[4][4];
    #pragma unroll
    for (int m2 = 0; m2 < 4; ++m2)
        #pragma unroll
        for (int nn = 0; nn < 4; ++nn)
            acc[m2][nn] = (f32x4){0.f, 0.f, 0.f, 0.f};

    uint4 va[4]; uint32_t mk[4];
    {
        #pragma unroll
        for (int q = 0; q < 4; ++q) { async16((char*)sB[0] + ldsBo[q], pBq[q]); pBq[q] += 128; }
        #pragma unroll
        for (int q = 0; q < 4; ++q) { async16((char*)sB[1] + ldsBo[q], pBq[q]); pBq[q] += 128; }
        #pragma unroll
        for (int p = 0; p < 4; ++p) { va[p] = *(const uint4*)pXA[p]; mk[p] = *pMA[p];
                                      pXA[p] += 64; pMA[p] += 8; }
        #pragma unroll
        for (int p = 0; p < 4; ++p) {
            uint4 z;
            z.x = va[p].x & bexp(mk[p], 0); z.y = va[p].y & bexp(mk[p], 1);
            z.z = va[p].z & bexp(mk[p], 2); z.w = va[p].w & bexp(mk[p], 3);
            *(uint4*)((char*)sA[0] + awz[p]) = z;
        }
        #pragma unroll
        for (int p = 0; p < 4; ++p) { va[p] = *(const uint4*)pXA[p]; mk[p] = *pMA[p];
                                      pXA[p] += 64; pMA[p] += 8; }
        asm volatile("s_waitcnt lgkmcnt(0)" ::: "memory");
        __builtin_amdgcn_s_barrier();
    }
    for (int t = 0; t < NT5; ++t) {
        if (t + 2 < NT5) {
            int buf = (t + 2) % 3;
            #pragma unroll
            for (int q = 0; q < 4; ++q) {
                async16((char*)sB[buf] + ldsBo[q], pBq[q]);
                pBq[q] += 128;
            }
        }
        const char* sAc = (const char*)sA[t & 1];
        const char* sBc = (const char*)sB[t % 3];
        __builtin_amdgcn_s_setprio(1);
        #pragma unroll
        for (int ks = 0; ks < 2; ++ks) {
            int kb = ks * 64 + (lgrp << 4);
            bf16x8 af[4], bfr[4];
            #pragma unroll
            for (int m2 = 0; m2 < 4; ++m2) {
                int row = wr * 64 + m2 * 16 + lrow;
                af[m2] = *(const bf16x8*)(sAc + row * 128 + (kb ^ ((row & 7) << 4)));
            }
            #pragma unroll
            for (int nn = 0; nn < 4; ++nn) {
                int col = wc * 64 + nn * 16 + lrow;
                bfr[nn] = *(const bf16x8*)(sBc + col * 128 + (kb ^ ((col & 7) << 4)));
            }
            #pragma unroll
            for (int m2 = 0; m2 < 4; ++m2)
                #pragma unroll
                for (int nn = 0; nn < 4; ++nn)
                    acc[m2][nn] = __builtin_amdgcn_mfma_f32_16x16x32_bf16(af[m2], bfr[nn], acc[m2][nn], 0, 0, 0);
        }
        __builtin_amdgcn_s_setprio(0);
        if (t + 1 < NT5) {
            #pragma unroll
            for (int p = 0; p < 4; ++p) {
                uint4 z;
                z.x = va[p].x & bexp(mk[p], 0); z.y = va[p].y & bexp(mk[p], 1);
                z.z = va[p].z & bexp(mk[p], 2); z.w = va[p].w & bexp(mk[p], 3);
                *(uint4*)((char*)sA[(t + 1) & 1] + awz[p]) = z;
            }
        }
        asm volatile("s_waitcnt vmcnt(4)" ::: "memory");
        if (t + 2 < NT5) {
            #pragma unroll
            for (int p = 0; p < 4; ++p) { va[p] = *(const uint4*)pXA[p]; mk[p] = *pMA[p];
                                          pXA[p] += 64; pMA[p] += 8; }
        }
        asm volatile("s_waitcnt lgkmcnt(0)" ::: "memory");
        __builtin_amdgcn_s_barrier();
    }
    #pragma unroll
    for (int nn = 0; nn < 4; ++nn) {
        int col = cbase + wc * 64 + nn * 16 + lrow;
        #pragma unroll
        for (int m2 = 0; m2 < 4; ++m2) {
            int rbase = r0 + wr * 64 + m2 * 16 + lgrp * 4;
            #pragma unroll
            for (int j = 0; j < 4; ++j)
                P[(size_t)(rbase + j) * OUT_DIM + col] = acc[m2][nn][j];
        }
    }
}

// ---------------- fallback: naive fp32 ---------------------------------------
__global__ __launch_bounds__(256) void k_naive(const float* __restrict__ x,
                                               const float* __restrict__ W,
                                               const float* __restrict__ th,
                                               const float* __restrict__ mu,
                                               const float* __restrict__ out_mu,
                                               float* __restrict__ out) {
    int idx = blockIdx.x * 256 + threadIdx.x;
    int r = idx >> 12;
    int c = idx & 4095;
    int n = c >> 7;
    float s = 0.f;
    for (int i = 0; i < I_DIM; ++i) {
        float xo = x[(size_t)r * I_DIM + i] - mu[i];
        if (fabsf(xo) >= th[i * N_STR + n])
            s += xo * W[(size_t)i * OUT_DIM + c];
    }
    out[idx] = s + out_mu[c];
}

extern "C" void kernel_launch(void* const* d_in, const int* in_sizes, int n_in,
                              void* d_out, int out_size, void* d_ws, size_t ws_size,
                              hipStream_t stream) {
    const float* x      = (const float*)d_in[0];
    const float* W      = (const float*)d_in[1];
    const float* th     = (const float*)d_in[2];
    const float* mu     = (const float*)d_in[3];
    const float* out_mu = (const float*)d_in[4];
    float* out = (float*)d_out;

    const size_t thT_b = (size_t)N_STR * I_DIM * sizeof(float);      // 0.5 MiB
    const size_t wT_b  = (size_t)OUT_DIM * I_DIM * sizeof(ushort);   // 32 MiB
    const size_t xb_b  = (size_t)R_TOTAL * I_DIM * sizeof(ushort);   // 8 MiB
    const size_t mb_b  = (size_t)N_STR * R_TOTAL * 512;              // 16 MiB
    const size_t p_b   = (size_t)R_TOTAL * OUT_DIM * sizeof(float);  // 16 MiB each

    ushort*  WT  = (ushort*)((char*)d_ws + thT_b);
    ushort*  XBp = (ushort*)((char*)d_ws + thT_b + wT_b);
    uint8_t* MBp = (uint8_t*)((char*)d_ws + thT_b + wT_b + xb_b);
    float*   P1  = (float*)((char*)d_ws + thT_b + wT_b + xb_b + mb_b);
    float*   P2  = (float*)((char*)d_ws + thT_b + wT_b + xb_b + mb_b + p_b);

    if (ws_size >= thT_b + wT_b + xb_b + mb_b + 2 * p_b) {
        // fast path: merged pre-pass, 3-blocks/CU split-K=3 main, reduce
        k_prep3<<<4096 + 2048, 256, 0, stream>>>(W, WT, x, mu, th, XBp,
                                                 (unsigned long long*)MBp);
        k_main8<<<768, 256, 0, stream>>>(XBp, WT, MBp, out, P1, P2);
        k_reduce3<<<(R_TOTAL * OUT_DIM / 4) / 256, 256, 0, stream>>>(out, P1, P2, out_mu);
    } else if (ws_size >= thT_b + wT_b + xb_b + mb_b + p_b) {
        k_prep3<<<4096 + 2048, 256, 0, stream>>>(W, WT, x, mu, th, XBp,
                                                 (unsigned long long*)MBp);
        k_main5<<<512, 256, 0, stream>>>(XBp, WT, MBp, out, P1);
        k_reduce<<<(R_TOTAL * OUT_DIM / 4) / 256, 256, 0, stream>>>(out, P1, out_mu);
    } else {
        k_naive<<<(R_TOTAL * OUT_DIM) / 256, 256, 0, stream>>>(x, W, th, mu, out_mu, out);
    }
}

// Round 10
// 103.043 us; speedup vs baseline: 1.2381x; 1.0648x over previous
//
#include <hip/hip_runtime.h>
#include <hip/hip_bf16.h>
#include <stdint.h>

// Problem dims (fixed by reference)
#define R_TOTAL 1024      // B*S
#define I_DIM   4096
#define OUT_DIM 4096
#define N_STR   32
#define Q_DIM   128

typedef __attribute__((ext_vector_type(8))) __bf16 bf16x8;
typedef __attribute__((ext_vector_type(4))) float  f32x4;

__device__ __forceinline__ ushort f2bf(float f) {
    uint32_t u = __float_as_uint(f);
    uint32_t r = (u + 0x7fffu + ((u >> 16) & 1u)) >> 16;   // RNE
    return (ushort)r;
}

__device__ __forceinline__ float bf2f(ushort u) {
    return __uint_as_float((uint32_t)u << 16);
}

// expand 2 mask bits (2w, 2w+1) -> 32-bit AND-mask for a packed bf16 pair
__device__ __forceinline__ uint32_t bexp(uint32_t b, int w) {
    return ((b >> (2 * w)) & 1u) * 0xFFFFu | ((b >> (2 * w + 1)) & 1u) * 0xFFFF0000u;
}

__device__ __forceinline__ void async16(void* lds, const void* g) {
    __builtin_amdgcn_global_load_lds(
        (const __attribute__((address_space(1))) unsigned int*)g,
        (__attribute__((address_space(3))) unsigned int*)lds, 16, 0, 0);
}

// ================= pre-pass bodies ===========================================

// W [I][OUT] f32 -> WT [OUT][I] bf16, one 64x64 tile
__device__ __forceinline__ void transpose_w_block(const float* __restrict__ W,
                                                  ushort* __restrict__ WT,
                                                  int c0, int i0, int t,
                                                  float (*tile)[65]) {
    {
        int dc4 = (t & 15) * 4;
        int di  = t >> 4;
        #pragma unroll
        for (int p = 0; p < 4; ++p) {
            int ii = di + p * 16;
            float4 v = *(const float4*)(W + (size_t)(i0 + ii) * OUT_DIM + c0 + dc4);
            tile[ii][dc4 + 0] = v.x; tile[ii][dc4 + 1] = v.y;
            tile[ii][dc4 + 2] = v.z; tile[ii][dc4 + 3] = v.w;
        }
    }
    __syncthreads();
    {
        int iq = (t & 15) * 4;
        int dc = t >> 4;
        #pragma unroll
        for (int p = 0; p < 4; ++p) {
            int cc = dc + p * 16;
            ushort4 o;
            o.x = f2bf(tile[iq + 0][cc]);
            o.y = f2bf(tile[iq + 1][cc]);
            o.z = f2bf(tile[iq + 2][cc]);
            o.w = f2bf(tile[iq + 3][cc]);
            *(ushort4*)(WT + (size_t)(c0 + cc) * I_DIM + i0 + iq) = o;
        }
    }
}

// XB = bf16(x-mu) + per-stripe bitmasks. v4: thresholds hoisted upfront (one
// latency exposure); per stripe, 8 row-ballots batched into SGPRs and stored
// under ONE lane0 guard (32 exec toggles/wave instead of 256). LDS mask layout
// [n][wave][rr] so the guarded store is 64B contiguous; masks + XB written
// coalesced. Proven R8 ballot->store semantics, no inline-asm packing.
__device__ __forceinline__ void prep_block4(const float* __restrict__ x,
                                            const float* __restrict__ mu,
                                            const float* __restrict__ th,
                                            ushort* __restrict__ XB,
                                            unsigned long long* __restrict__ MB64,
                                            int rb, int ib, int tid,
                                            char* smem) {
    ushort* sXB = (ushort*)smem;                                  // 4 KB
    unsigned long long* sMB = (unsigned long long*)(smem + 4096); // 8 KB, [n][wave][rr]
    int i = ib * 256 + tid;
    int lane = tid & 63;
    int wave = tid >> 6;

    // ---- all 32 thresholds for this i, loaded upfront (8 independent loads)
    float4 tq[8];
    #pragma unroll
    for (int q = 0; q < 8; ++q)
        tq[q] = *(const float4*)(th + (size_t)i * N_STR + q * 4);

    float muv = mu[i];
    float ax[8];
    #pragma unroll
    for (int rr = 0; rr < 8; ++rr) {
        float xo = x[(size_t)(rb * 8 + rr) * I_DIM + i] - muv;
        sXB[rr * 256 + tid] = f2bf(xo);
        ax[rr] = fabsf(xo);
    }

    #pragma unroll
    for (int n = 0; n < N_STR; ++n) {
        float4 v = tq[n >> 2];
        float tn = (n & 3) == 0 ? v.x : (n & 3) == 1 ? v.y : (n & 3) == 2 ? v.z : v.w;
        unsigned long long bal[8];
        #pragma unroll
        for (int rr = 0; rr < 8; ++rr)
            bal[rr] = __ballot(ax[rr] >= tn);
        if (lane == 0) {
            #pragma unroll
            for (int rr = 0; rr < 8; ++rr)
                sMB[(n * 4 + wave) * 8 + rr] = bal[rr];
        }
    }
    __syncthreads();

    // ---- coalesced XB write: thread -> (row, 16B segment)
    {
        int row = tid >> 5, seg = tid & 31;
        uint4 v = *(const uint4*)&sXB[row * 256 + seg * 8];
        *(uint4*)(XB + (size_t)(rb * 8 + row) * I_DIM + ib * 256 + seg * 8) = v;
    }
    // ---- mask write: thread -> (n, rr); gather per-wave u64s, 32B store
    {
        int n = tid >> 3, rr = tid & 7;
        unsigned long long v0 = sMB[(n * 4 + 0) * 8 + rr];
        unsigned long long v1 = sMB[(n * 4 + 1) * 8 + rr];
        unsigned long long v2 = sMB[(n * 4 + 2) * 8 + rr];
        unsigned long long v3 = sMB[(n * 4 + 3) * 8 + rr];
        unsigned long long* dst = MB64 + ((size_t)n * R_TOTAL + rb * 8 + rr) * 64 + ib * 4;
        dst[0] = v0; dst[1] = v1; dst[2] = v2; dst[3] = v3;
    }
}

// ---------------- merged pre-pass: transpose_w (0..4095) + prep (4096..6143) -
__global__ __launch_bounds__(256) void k_prep5(const float* __restrict__ W,
                                               ushort* __restrict__ WT,
                                               const float* __restrict__ x,
                                               const float* __restrict__ mu,
                                               const float* __restrict__ th,
                                               ushort* __restrict__ XB,
                                               unsigned long long* __restrict__ MB64) {
    __shared__ __align__(16) float smem[64 * 65];   // 16.25 KB, reused by both
    int b = blockIdx.x;
    int t = threadIdx.x;
    if (b < 4096) {
        transpose_w_block(W, WT, (b & 63) * 64, (b >> 6) * 64, t,
                          (float (*)[65])smem);
    } else {
        b -= 4096;                      // 0..2047
        prep_block4(x, mu, th, XB, MB64, b >> 4, b & 15, t, (char*)smem);
    }
}

// ---------------- main v9: R8 structure, bf16 partial epilogue ---------------
// tile 128x128, 4 waves of 64x64, BK=64. sA single (16K) + sB dbuf (32K)
// = 48 KB -> 3 blocks/CU. Split-K=3 uneven: 22/21/21 steps of BK=64.

__global__ __launch_bounds__(256, 3) void k_main9(const ushort* __restrict__ XB,
                                                  const ushort* __restrict__ WT,
                                                  const uint8_t* __restrict__ MB,
                                                  ushort* __restrict__ PB0,
                                                  ushort* __restrict__ PB1,
                                                  ushort* __restrict__ PB2) {
    __shared__ ushort sA[128 * 64];      // 16 KB (single)
    __shared__ ushort sB[2][128 * 64];   // 16 KB each

    int bid  = blockIdx.x;               // 0..767
    int xcd  = bid & 7;
    int slot = bid >> 3;                 // 0..95
    int n    = xcd * 4 + (slot & 3);     // stripe (XCD-local group of 4)
    int rt   = (slot >> 2) & 7;          // row tile 0..7
    int kq   = slot >> 5;                // 0..2
    int r0   = rt * 128;
    int k0   = (kq == 0) ? 0 : (kq == 1) ? 1408 : 2752;
    int NT   = (kq == 0) ? 22 : 21;
    int cbase = n * Q_DIM;
    ushort* P = (kq == 0) ? PB0 : (kq == 1) ? PB1 : PB2;

    int tid  = threadIdx.x;
    int lane = tid & 63;
    int wave = tid >> 6;                 // 0..3
    int wr   = wave >> 1;                // 0..1 : 64-row group
    int wc   = wave & 1;                 // 0..1 : 64-col group
    int lrow = lane & 15;
    int lgrp = lane >> 4;

    // ---- A staging maps: pass p: row = p*32 + (tid>>3), 8 elems
    const ushort*  pXA[4];
    const uint8_t* pMA[4];
    int awz[4];
    {
        int ar = tid >> 3;
        int ak = (tid & 7) * 8;
        #pragma unroll
        for (int p = 0; p < 4; ++p) {
            int row = p * 32 + ar;
            pXA[p] = XB + (size_t)(r0 + row) * I_DIM + k0 + ak;
            pMA[p] = MB + ((size_t)n * R_TOTAL + r0 + row) * 512 + (k0 >> 3) + (tid & 7);
            awz[p] = row * 128 + ((ak * 2) ^ ((row & 7) << 4));
        }
    }

    // ---- B staging maps: 16 chunks of 1KB; pre-swizzled source
    const char* pBq[4];
    int ldsBo[4];
    #pragma unroll
    for (int q = 0; q < 4; ++q) {
        int chunk = wave * 4 + q;
        int col = chunk * 8 + (lane >> 3);
        pBq[q] = (const char*)WT + (size_t)(cbase + col) * (I_DIM * 2)
               + (size_t)k0 * 2 + (((lane & 7) ^ (lane >> 3)) << 4);
        ldsBo[q] = chunk * 1024;
    }

    f32x4 acc[4][4];
    #pragma unroll
    for (int m2 = 0; m2 < 4; ++m2)
        #pragma unroll
        for (int nn = 0; nn < 4; ++nn)
            acc[m2][nn] = (f32x4){0.f, 0.f, 0.f, 0.f};

    uint4 va[4]; uint32_t mk[4];

    // ---- prologue: A0 regs; B0 DMA; write sA(0); A1 regs; barrier
    #pragma unroll
    for (int p = 0; p < 4; ++p) { va[p] = *(const uint4*)pXA[p]; mk[p] = *pMA[p]; }
    #pragma unroll
    for (int q = 0; q < 4; ++q) async16((char*)sB[0] + ldsBo[q], pBq[q]);
    #pragma unroll
    for (int p = 0; p < 4; ++p) {
        uint4 z;
        z.x = va[p].x & bexp(mk[p], 0); z.y = va[p].y & bexp(mk[p], 1);
        z.z = va[p].z & bexp(mk[p], 2); z.w = va[p].w & bexp(mk[p], 3);
        *(uint4*)((char*)sA + awz[p]) = z;
    }
    #pragma unroll
    for (int p = 0; p < 4; ++p) { va[p] = *(const uint4*)(pXA[p] + 64); mk[p] = *(pMA[p] + 8); }
    __syncthreads();                     // sA(0), sB[0] ready

    for (int t = 0; t < NT; ++t) {
        // issue B(t+1) DMA into the other sB buffer (lands under compute)
        if (t + 1 < NT) {
            #pragma unroll
            for (int q = 0; q < 4; ++q)
                async16((char*)sB[(t + 1) & 1] + ldsBo[q],
                        pBq[q] + (size_t)(t + 1) * 128);
        }
        // ---- compute tile t (sA single, sB[t&1])
        const char* sAc = (const char*)sA;
        const char* sBc = (const char*)sB[t & 1];
        __builtin_amdgcn_s_setprio(1);
        #pragma unroll
        for (int ks = 0; ks < 2; ++ks) {
            int kb = ks * 64 + (lgrp << 4);
            bf16x8 af[4], bfr[4];
            #pragma unroll
            for (int m2 = 0; m2 < 4; ++m2) {
                int row = wr * 64 + m2 * 16 + lrow;
                af[m2] = *(const bf16x8*)(sAc + row * 128 + (kb ^ ((row & 7) << 4)));
            }
            #pragma unroll
            for (int nn = 0; nn < 4; ++nn) {
                int col = wc * 64 + nn * 16 + lrow;
                bfr[nn] = *(const bf16x8*)(sBc + col * 128 + (kb ^ ((col & 7) << 4)));
            }
            #pragma unroll
            for (int m2 = 0; m2 < 4; ++m2)
                #pragma unroll
                for (int nn = 0; nn < 4; ++nn)
                    acc[m2][nn] = __builtin_amdgcn_mfma_f32_16x16x32_bf16(af[m2], bfr[nn], acc[m2][nn], 0, 0, 0);
        }
        __builtin_amdgcn_s_setprio(0);
        __syncthreads();                 // compute done; B(t+1)+A-regs drained
        // ---- write sA(t+1); prefetch A(t+2) regs
        if (t + 1 < NT) {
            #pragma unroll
            for (int p = 0; p < 4; ++p) {
                uint4 z;
                z.x = va[p].x & bexp(mk[p], 0); z.y = va[p].y & bexp(mk[p], 1);
                z.z = va[p].z & bexp(mk[p], 2); z.w = va[p].w & bexp(mk[p], 3);
                *(uint4*)((char*)sA + awz[p]) = z;
            }
            if (t + 2 < NT) {
                #pragma unroll
                for (int p = 0; p < 4; ++p) {
                    va[p] = *(const uint4*)(pXA[p] + (size_t)(t + 2) * 64);
                    mk[p] = *(pMA[p] + (size_t)(t + 2) * 8);
                }
            }
        }
        __syncthreads();                 // sA(t+1) visible
    }

    // ---- epilogue: bf16 partials (summed + out_mu added in k_reduce3b)
    #pragma unroll
    for (int nn = 0; nn < 4; ++nn) {
        int col = cbase + wc * 64 + nn * 16 + lrow;
        #pragma unroll
        for (int m2 = 0; m2 < 4; ++m2) {
            int rbase = r0 + wr * 64 + m2 * 16 + lgrp * 4;
            #pragma unroll
            for (int j = 0; j < 4; ++j)
                P[(size_t)(rbase + j) * OUT_DIM + col] = f2bf(acc[m2][nn][j]);
        }
    }
}

// ---------------- reduce: out = PB0 + PB1 + PB2 + out_mu (bf16 partials) -----
__global__ __launch_bounds__(256) void k_reduce3b(float* __restrict__ out,
                                                  const ushort* __restrict__ PB0,
                                                  const ushort* __restrict__ PB1,
                                                  const ushort* __restrict__ PB2,
                                                  const float* __restrict__ out_mu) {
    int idx = blockIdx.x * 256 + threadIdx.x;       // 8-elem group, 524288 total
    uint4 a = *(const uint4*)(PB0 + (size_t)idx * 8);
    uint4 b = *(const uint4*)(PB1 + (size_t)idx * 8);
    uint4 c = *(const uint4*)(PB2 + (size_t)idx * 8);
    const float* om = out_mu + (idx & 511) * 8;
    float4 m0 = *(const float4*)om;
    float4 m1 = *(const float4*)(om + 4);
    float4 o0, o1;
    o0.x = bf2f((ushort)(a.x & 0xFFFF)) + bf2f((ushort)(b.x & 0xFFFF)) + bf2f((ushort)(c.x & 0xFFFF)) + m0.x;
    o0.y = bf2f((ushort)(a.x >> 16))    + bf2f((ushort)(b.x >> 16))    + bf2f((ushort)(c.x >> 16))    + m0.y;
    o0.z = bf2f((ushort)(a.y & 0xFFFF)) + bf2f((ushort)(b.y & 0xFFFF)) + bf2f((ushort)(c.y & 0xFFFF)) + m0.z;
    o0.w = bf2f((ushort)(a.y >> 16))    + bf2f((ushort)(b.y >> 16))    + bf2f((ushort)(c.y >> 16))    + m0.w;
    o1.x = bf2f((ushort)(a.z & 0xFFFF)) + bf2f((ushort)(b.z & 0xFFFF)) + bf2f((ushort)(c.z & 0xFFFF)) + m1.x;
    o1.y = bf2f((ushort)(a.z >> 16))    + bf2f((ushort)(b.z >> 16))    + bf2f((ushort)(c.z >> 16))    + m1.y;
    o1.z = bf2f((ushort)(a.w & 0xFFFF)) + bf2f((ushort)(b.w & 0xFFFF)) + bf2f((ushort)(c.w & 0xFFFF)) + m1.z;
    o1.w = bf2f((ushort)(a.w >> 16))    + bf2f((ushort)(b.w >> 16))    + bf2f((ushort)(c.w >> 16))    + m1.w;
    float* dst = out + (size_t)idx * 8;
    *(float4*)dst = o0;
    *(float4*)(dst + 4) = o1;
}

// ---------------- fallback: naive fp32 ---------------------------------------
__global__ __launch_bounds__(256) void k_naive(const float* __restrict__ x,
                                               const float* __restrict__ W,
                                               const float* __restrict__ th,
                                               const float* __restrict__ mu,
                                               const float* __restrict__ out_mu,
                                               float* __restrict__ out) {
    int idx = blockIdx.x * 256 + threadIdx.x;
    int r = idx >> 12;
    int c = idx & 4095;
    int n = c >> 7;
    float s = 0.f;
    for (int i = 0; i < I_DIM; ++i) {
        float xo = x[(size_t)r * I_DIM + i] - mu[i];
        if (fabsf(xo) >= th[i * N_STR + n])
            s += xo * W[(size_t)i * OUT_DIM + c];
    }
    out[idx] = s + out_mu[c];
}

extern "C" void kernel_launch(void* const* d_in, const int* in_sizes, int n_in,
                              void* d_out, int out_size, void* d_ws, size_t ws_size,
                              hipStream_t stream) {
    const float* x      = (const float*)d_in[0];
    const float* W      = (const float*)d_in[1];
    const float* th     = (const float*)d_in[2];
    const float* mu     = (const float*)d_in[3];
    const float* out_mu = (const float*)d_in[4];
    float* out = (float*)d_out;

    const size_t wT_b = (size_t)OUT_DIM * I_DIM * sizeof(ushort);   // 32 MiB
    const size_t xb_b = (size_t)R_TOTAL * I_DIM * sizeof(ushort);   // 8 MiB
    const size_t mb_b = (size_t)N_STR * R_TOTAL * 512;              // 16 MiB
    const size_t pb_b = (size_t)R_TOTAL * OUT_DIM * sizeof(ushort); // 8 MiB each

    ushort*  WT  = (ushort*)d_ws;
    ushort*  XBp = (ushort*)((char*)d_ws + wT_b);
    uint8_t* MBp = (uint8_t*)((char*)d_ws + wT_b + xb_b);
    ushort*  PB0 = (ushort*)((char*)d_ws + wT_b + xb_b + mb_b);
    ushort*  PB1 = (ushort*)((char*)d_ws + wT_b + xb_b + mb_b + pb_b);
    ushort*  PB2 = (ushort*)((char*)d_ws + wT_b + xb_b + mb_b + 2 * pb_b);

    if (ws_size >= wT_b + xb_b + mb_b + 3 * pb_b) {
        k_prep5<<<4096 + 2048, 256, 0, stream>>>(W, WT, x, mu, th, XBp,
                                                 (unsigned long long*)MBp);
        k_main9<<<768, 256, 0, stream>>>(XBp, WT, MBp, PB0, PB1, PB2);
        k_reduce3b<<<(R_TOTAL * OUT_DIM / 8) / 256, 256, 0, stream>>>(out, PB0, PB1, PB2, out_mu);
    } else {
        k_naive<<<(R_TOTAL * OUT_DIM) / 256, 256, 0, stream>>>(x, W, th, mu, out_mu, out);
    }
}

// Round 11
// 102.314 us; speedup vs baseline: 1.2469x; 1.0071x over previous
//
#include <hip/hip_runtime.h>
#include <hip/hip_bf16.h>
#include <stdint.h>

// Problem dims (fixed by reference)
#define R_TOTAL 1024      // B*S
#define I_DIM   4096
#define OUT_DIM 4096
#define N_STR   32
#define Q_DIM   128

typedef __attribute__((ext_vector_type(8))) __bf16 bf16x8;
typedef __attribute__((ext_vector_type(4))) float  f32x4;

__device__ __forceinline__ ushort f2bf(float f) {
    uint32_t u = __float_as_uint(f);
    uint32_t r = (u + 0x7fffu + ((u >> 16) & 1u)) >> 16;   // RNE
    return (ushort)r;
}

__device__ __forceinline__ float bf2f(ushort u) {
    return __uint_as_float((uint32_t)u << 16);
}

// expand 2 mask bits (2w, 2w+1) -> 32-bit AND-mask for a packed bf16 pair
__device__ __forceinline__ uint32_t bexp(uint32_t b, int w) {
    return ((b >> (2 * w)) & 1u) * 0xFFFFu | ((b >> (2 * w + 1)) & 1u) * 0xFFFF0000u;
}

__device__ __forceinline__ void async16(void* lds, const void* g) {
    __builtin_amdgcn_global_load_lds(
        (const __attribute__((address_space(1))) unsigned int*)g,
        (__attribute__((address_space(3))) unsigned int*)lds, 16, 0, 0);
}

// ================= pre-pass bodies ===========================================

// W [I][OUT] f32 -> WT [OUT][I] bf16, one 64x64 tile
__device__ __forceinline__ void transpose_w_block(const float* __restrict__ W,
                                                  ushort* __restrict__ WT,
                                                  int c0, int i0, int t,
                                                  float (*tile)[65]) {
    {
        int dc4 = (t & 15) * 4;
        int di  = t >> 4;
        #pragma unroll
        for (int p = 0; p < 4; ++p) {
            int ii = di + p * 16;
            float4 v = *(const float4*)(W + (size_t)(i0 + ii) * OUT_DIM + c0 + dc4);
            tile[ii][dc4 + 0] = v.x; tile[ii][dc4 + 1] = v.y;
            tile[ii][dc4 + 2] = v.z; tile[ii][dc4 + 3] = v.w;
        }
    }
    __syncthreads();
    {
        int iq = (t & 15) * 4;
        int dc = t >> 4;
        #pragma unroll
        for (int p = 0; p < 4; ++p) {
            int cc = dc + p * 16;
            ushort4 o;
            o.x = f2bf(tile[iq + 0][cc]);
            o.y = f2bf(tile[iq + 1][cc]);
            o.z = f2bf(tile[iq + 2][cc]);
            o.w = f2bf(tile[iq + 3][cc]);
            *(ushort4*)(WT + (size_t)(c0 + cc) * I_DIM + i0 + iq) = o;
        }
    }
}

// XB = bf16(x-mu) + per-stripe bitmasks (R10-proven body)
__device__ __forceinline__ void prep_block4(const float* __restrict__ x,
                                            const float* __restrict__ mu,
                                            const float* __restrict__ th,
                                            ushort* __restrict__ XB,
                                            unsigned long long* __restrict__ MB64,
                                            int rb, int ib, int tid,
                                            char* smem) {
    ushort* sXB = (ushort*)smem;                                  // 4 KB
    unsigned long long* sMB = (unsigned long long*)(smem + 4096); // 8 KB, [n][wave][rr]
    int i = ib * 256 + tid;
    int lane = tid & 63;
    int wave = tid >> 6;

    // ---- all 32 thresholds for this i, loaded upfront (8 independent loads)
    float4 tq[8];
    #pragma unroll
    for (int q = 0; q < 8; ++q)
        tq[q] = *(const float4*)(th + (size_t)i * N_STR + q * 4);

    float muv = mu[i];
    float ax[8];
    #pragma unroll
    for (int rr = 0; rr < 8; ++rr) {
        float xo = x[(size_t)(rb * 8 + rr) * I_DIM + i] - muv;
        sXB[rr * 256 + tid] = f2bf(xo);
        ax[rr] = fabsf(xo);
    }

    #pragma unroll
    for (int n = 0; n < N_STR; ++n) {
        float4 v = tq[n >> 2];
        float tn = (n & 3) == 0 ? v.x : (n & 3) == 1 ? v.y : (n & 3) == 2 ? v.z : v.w;
        unsigned long long bal[8];
        #pragma unroll
        for (int rr = 0; rr < 8; ++rr)
            bal[rr] = __ballot(ax[rr] >= tn);
        if (lane == 0) {
            #pragma unroll
            for (int rr = 0; rr < 8; ++rr)
                sMB[(n * 4 + wave) * 8 + rr] = bal[rr];
        }
    }
    __syncthreads();

    // ---- coalesced XB write: thread -> (row, 16B segment)
    {
        int row = tid >> 5, seg = tid & 31;
        uint4 v = *(const uint4*)&sXB[row * 256 + seg * 8];
        *(uint4*)(XB + (size_t)(rb * 8 + row) * I_DIM + ib * 256 + seg * 8) = v;
    }
    // ---- mask write: thread -> (n, rr); gather per-wave u64s, 32B store
    {
        int n = tid >> 3, rr = tid & 7;
        unsigned long long v0 = sMB[(n * 4 + 0) * 8 + rr];
        unsigned long long v1 = sMB[(n * 4 + 1) * 8 + rr];
        unsigned long long v2 = sMB[(n * 4 + 2) * 8 + rr];
        unsigned long long v3 = sMB[(n * 4 + 3) * 8 + rr];
        unsigned long long* dst = MB64 + ((size_t)n * R_TOTAL + rb * 8 + rr) * 64 + ib * 4;
        dst[0] = v0; dst[1] = v1; dst[2] = v2; dst[3] = v3;
    }
}

// ---------------- merged pre-pass, INTERLEAVED block mapping -----------------
// 6144 blocks. Every 3rd block (b%3==2) is a prep block (2048 total); the rest
// are transpose blocks (4096 total, tb = (b/3)*2 + (b%3), bijective). This
// overlaps the BW-bound W-transpose with the VALU/latency-bound prep instead
// of running them as two serial phases (R10: segregated IDs -> serialized).
__global__ __launch_bounds__(256) void k_prep6(const float* __restrict__ W,
                                               ushort* __restrict__ WT,
                                               const float* __restrict__ x,
                                               const float* __restrict__ mu,
                                               const float* __restrict__ th,
                                               ushort* __restrict__ XB,
                                               unsigned long long* __restrict__ MB64) {
    __shared__ __align__(16) float smem[64 * 65];   // 16.25 KB, reused by both
    int b = blockIdx.x;
    int t = threadIdx.x;
    int g = b / 3;
    int r = b - g * 3;
    if (r == 2) {
        // prep block index g in 0..2047
        prep_block4(x, mu, th, XB, MB64, g >> 4, g & 15, t, (char*)smem);
    } else {
        int tb = g * 2 + r;             // 0..4095
        transpose_w_block(W, WT, (tb & 63) * 64, (tb >> 6) * 64, t,
                          (float (*)[65])smem);
    }
}

// ---------------- main v9: R8 structure, bf16 partial epilogue ---------------
// tile 128x128, 4 waves of 64x64, BK=64. sA single (16K) + sB dbuf (32K)
// = 48 KB -> 3 blocks/CU. Split-K=3 uneven: 22/21/21 steps of BK=64.

__global__ __launch_bounds__(256, 3) void k_main9(const ushort* __restrict__ XB,
                                                  const ushort* __restrict__ WT,
                                                  const uint8_t* __restrict__ MB,
                                                  ushort* __restrict__ PB0,
                                                  ushort* __restrict__ PB1,
                                                  ushort* __restrict__ PB2) {
    __shared__ ushort sA[128 * 64];      // 16 KB (single)
    __shared__ ushort sB[2][128 * 64];   // 16 KB each

    int bid  = blockIdx.x;               // 0..767
    int xcd  = bid & 7;
    int slot = bid >> 3;                 // 0..95
    int n    = xcd * 4 + (slot & 3);     // stripe (XCD-local group of 4)
    int rt   = (slot >> 2) & 7;          // row tile 0..7
    int kq   = slot >> 5;                // 0..2
    int r0   = rt * 128;
    int k0   = (kq == 0) ? 0 : (kq == 1) ? 1408 : 2752;
    int NT   = (kq == 0) ? 22 : 21;
    int cbase = n * Q_DIM;
    ushort* P = (kq == 0) ? PB0 : (kq == 1) ? PB1 : PB2;

    int tid  = threadIdx.x;
    int lane = tid & 63;
    int wave = tid >> 6;                 // 0..3
    int wr   = wave >> 1;                // 0..1 : 64-row group
    int wc   = wave & 1;                 // 0..1 : 64-col group
    int lrow = lane & 15;
    int lgrp = lane >> 4;

    // ---- A staging maps: pass p: row = p*32 + (tid>>3), 8 elems
    const ushort*  pXA[4];
    const uint8_t* pMA[4];
    int awz[4];
    {
        int ar = tid >> 3;
        int ak = (tid & 7) * 8;
        #pragma unroll
        for (int p = 0; p < 4; ++p) {
            int row = p * 32 + ar;
            pXA[p] = XB + (size_t)(r0 + row) * I_DIM + k0 + ak;
            pMA[p] = MB + ((size_t)n * R_TOTAL + r0 + row) * 512 + (k0 >> 3) + (tid & 7);
            awz[p] = row * 128 + ((ak * 2) ^ ((row & 7) << 4));
        }
    }

    // ---- B staging maps: 16 chunks of 1KB; pre-swizzled source
    const char* pBq[4];
    int ldsBo[4];
    #pragma unroll
    for (int q = 0; q < 4; ++q) {
        int chunk = wave * 4 + q;
        int col = chunk * 8 + (lane >> 3);
        pBq[q] = (const char*)WT + (size_t)(cbase + col) * (I_DIM * 2)
               + (size_t)k0 * 2 + (((lane & 7) ^ (lane >> 3)) << 4);
        ldsBo[q] = chunk * 1024;
    }

    f32x4 acc[4][4];
    #pragma unroll
    for (int m2 = 0; m2 < 4; ++m2)
        #pragma unroll
        for (int nn = 0; nn < 4; ++nn)
            acc[m2][nn] = (f32x4){0.f, 0.f, 0.f, 0.f};

    uint4 va[4]; uint32_t mk[4];

    // ---- prologue: A0 regs; B0 DMA; write sA(0); A1 regs; barrier
    #pragma unroll
    for (int p = 0; p < 4; ++p) { va[p] = *(const uint4*)pXA[p]; mk[p] = *pMA[p]; }
    #pragma unroll
    for (int q = 0; q < 4; ++q) async16((char*)sB[0] + ldsBo[q], pBq[q]);
    #pragma unroll
    for (int p = 0; p < 4; ++p) {
        uint4 z;
        z.x = va[p].x & bexp(mk[p], 0); z.y = va[p].y & bexp(mk[p], 1);
        z.z = va[p].z & bexp(mk[p], 2); z.w = va[p].w & bexp(mk[p], 3);
        *(uint4*)((char*)sA + awz[p]) = z;
    }
    #pragma unroll
    for (int p = 0; p < 4; ++p) { va[p] = *(const uint4*)(pXA[p] + 64); mk[p] = *(pMA[p] + 8); }
    __syncthreads();                     // sA(0), sB[0] ready

    for (int t = 0; t < NT; ++t) {
        // issue B(t+1) DMA into the other sB buffer (lands under compute)
        if (t + 1 < NT) {
            #pragma unroll
            for (int q = 0; q < 4; ++q)
                async16((char*)sB[(t + 1) & 1] + ldsBo[q],
                        pBq[q] + (size_t)(t + 1) * 128);
        }
        // ---- compute tile t (sA single, sB[t&1])
        const char* sAc = (const char*)sA;
        const char* sBc = (const char*)sB[t & 1];
        __builtin_amdgcn_s_setprio(1);
        #pragma unroll
        for (int ks = 0; ks < 2; ++ks) {
            int kb = ks * 64 + (lgrp << 4);
            bf16x8 af[4], bfr[4];
            #pragma unroll
            for (int m2 = 0; m2 < 4; ++m2) {
                int row = wr * 64 + m2 * 16 + lrow;
                af[m2] = *(const bf16x8*)(sAc + row * 128 + (kb ^ ((row & 7) << 4)));
            }
            #pragma unroll
            for (int nn = 0; nn < 4; ++nn) {
                int col = wc * 64 + nn * 16 + lrow;
                bfr[nn] = *(const bf16x8*)(sBc + col * 128 + (kb ^ ((col & 7) << 4)));
            }
            #pragma unroll
            for (int m2 = 0; m2 < 4; ++m2)
                #pragma unroll
                for (int nn = 0; nn < 4; ++nn)
                    acc[m2][nn] = __builtin_amdgcn_mfma_f32_16x16x32_bf16(af[m2], bfr[nn], acc[m2][nn], 0, 0, 0);
        }
        __builtin_amdgcn_s_setprio(0);
        __syncthreads();                 // compute done; B(t+1)+A-regs drained
        // ---- write sA(t+1); prefetch A(t+2) regs
        if (t + 1 < NT) {
            #pragma unroll
            for (int p = 0; p < 4; ++p) {
                uint4 z;
                z.x = va[p].x & bexp(mk[p], 0); z.y = va[p].y & bexp(mk[p], 1);
                z.z = va[p].z & bexp(mk[p], 2); z.w = va[p].w & bexp(mk[p], 3);
                *(uint4*)((char*)sA + awz[p]) = z;
            }
            if (t + 2 < NT) {
                #pragma unroll
                for (int p = 0; p < 4; ++p) {
                    va[p] = *(const uint4*)(pXA[p] + (size_t)(t + 2) * 64);
                    mk[p] = *(pMA[p] + (size_t)(t + 2) * 8);
                }
            }
        }
        __syncthreads();                 // sA(t+1) visible
    }

    // ---- epilogue: bf16 partials (summed + out_mu added in k_reduce3b)
    #pragma unroll
    for (int nn = 0; nn < 4; ++nn) {
        int col = cbase + wc * 64 + nn * 16 + lrow;
        #pragma unroll
        for (int m2 = 0; m2 < 4; ++m2) {
            int rbase = r0 + wr * 64 + m2 * 16 + lgrp * 4;
            #pragma unroll
            for (int j = 0; j < 4; ++j)
                P[(size_t)(rbase + j) * OUT_DIM + col] = f2bf(acc[m2][nn][j]);
        }
    }
}

// ---------------- reduce: out = PB0 + PB1 + PB2 + out_mu (bf16 partials) -----
__global__ __launch_bounds__(256) void k_reduce3b(float* __restrict__ out,
                                                  const ushort* __restrict__ PB0,
                                                  const ushort* __restrict__ PB1,
                                                  const ushort* __restrict__ PB2,
                                                  const float* __restrict__ out_mu) {
    int idx = blockIdx.x * 256 + threadIdx.x;       // 8-elem group, 524288 total
    uint4 a = *(const uint4*)(PB0 + (size_t)idx * 8);
    uint4 b = *(const uint4*)(PB1 + (size_t)idx * 8);
    uint4 c = *(const uint4*)(PB2 + (size_t)idx * 8);
    const float* om = out_mu + (idx & 511) * 8;
    float4 m0 = *(const float4*)om;
    float4 m1 = *(const float4*)(om + 4);
    float4 o0, o1;
    o0.x = bf2f((ushort)(a.x & 0xFFFF)) + bf2f((ushort)(b.x & 0xFFFF)) + bf2f((ushort)(c.x & 0xFFFF)) + m0.x;
    o0.y = bf2f((ushort)(a.x >> 16))    + bf2f((ushort)(b.x >> 16))    + bf2f((ushort)(c.x >> 16))    + m0.y;
    o0.z = bf2f((ushort)(a.y & 0xFFFF)) + bf2f((ushort)(b.y & 0xFFFF)) + bf2f((ushort)(c.y & 0xFFFF)) + m0.z;
    o0.w = bf2f((ushort)(a.y >> 16))    + bf2f((ushort)(b.y >> 16))    + bf2f((ushort)(c.y >> 16))    + m0.w;
    o1.x = bf2f((ushort)(a.z & 0xFFFF)) + bf2f((ushort)(b.z & 0xFFFF)) + bf2f((ushort)(c.z & 0xFFFF)) + m1.x;
    o1.y = bf2f((ushort)(a.z >> 16))    + bf2f((ushort)(b.z >> 16))    + bf2f((ushort)(c.z >> 16))    + m1.y;
    o1.z = bf2f((ushort)(a.w & 0xFFFF)) + bf2f((ushort)(b.w & 0xFFFF)) + bf2f((ushort)(c.w & 0xFFFF)) + m1.z;
    o1.w = bf2f((ushort)(a.w >> 16))    + bf2f((ushort)(b.w >> 16))    + bf2f((ushort)(c.w >> 16))    + m1.w;
    float* dst = out + (size_t)idx * 8;
    *(float4*)dst = o0;
    *(float4*)(dst + 4) = o1;
}

// ---------------- fallback: naive fp32 ---------------------------------------
__global__ __launch_bounds__(256) void k_naive(const float* __restrict__ x,
                                               const float* __restrict__ W,
                                               const float* __restrict__ th,
                                               const float* __restrict__ mu,
                                               const float* __restrict__ out_mu,
                                               float* __restrict__ out) {
    int idx = blockIdx.x * 256 + threadIdx.x;
    int r = idx >> 12;
    int c = idx & 4095;
    int n = c >> 7;
    float s = 0.f;
    for (int i = 0; i < I_DIM; ++i) {
        float xo = x[(size_t)r * I_DIM + i] - mu[i];
        if (fabsf(xo) >= th[i * N_STR + n])
            s += xo * W[(size_t)i * OUT_DIM + c];
    }
    out[idx] = s + out_mu[c];
}

extern "C" void kernel_launch(void* const* d_in, const int* in_sizes, int n_in,
                              void* d_out, int out_size, void* d_ws, size_t ws_size,
                              hipStream_t stream) {
    const float* x      = (const float*)d_in[0];
    const float* W      = (const float*)d_in[1];
    const float* th     = (const float*)d_in[2];
    const float* mu     = (const float*)d_in[3];
    const float* out_mu = (const float*)d_in[4];
    float* out = (float*)d_out;

    const size_t wT_b = (size_t)OUT_DIM * I_DIM * sizeof(ushort);   // 32 MiB
    const size_t xb_b = (size_t)R_TOTAL * I_DIM * sizeof(ushort);   // 8 MiB
    const size_t mb_b = (size_t)N_STR * R_TOTAL * 512;              // 16 MiB
    const size_t pb_b = (size_t)R_TOTAL * OUT_DIM * sizeof(ushort); // 8 MiB each

    ushort*  WT  = (ushort*)d_ws;
    ushort*  XBp = (ushort*)((char*)d_ws + wT_b);
    uint8_t* MBp = (uint8_t*)((char*)d_ws + wT_b + xb_b);
    ushort*  PB0 = (ushort*)((char*)d_ws + wT_b + xb_b + mb_b);
    ushort*  PB1 = (ushort*)((char*)d_ws + wT_b + xb_b + mb_b + pb_b);
    ushort*  PB2 = (ushort*)((char*)d_ws + wT_b + xb_b + mb_b + 2 * pb_b);

    if (ws_size >= wT_b + xb_b + mb_b + 3 * pb_b) {
        k_prep6<<<6144, 256, 0, stream>>>(W, WT, x, mu, th, XBp,
                                          (unsigned long long*)MBp);
        k_main9<<<768, 256, 0, stream>>>(XBp, WT, MBp, PB0, PB1, PB2);
        k_reduce3b<<<(R_TOTAL * OUT_DIM / 8) / 256, 256, 0, stream>>>(out, PB0, PB1, PB2, out_mu);
    } else {
        k_naive<<<(R_TOTAL * OUT_DIM) / 256, 256, 0, stream>>>(x, W, th, mu, out_mu, out);
    }
}

// Round 12
// 87.333 us; speedup vs baseline: 1.4608x; 1.1715x over previous
//
#include <hip/hip_runtime.h>
#include <hip/hip_bf16.h>
#include <stdint.h>

// Problem dims (fixed by reference)
#define R_TOTAL 1024      // B*S
#define I_DIM   4096
#define OUT_DIM 4096
#define N_STR   32
#define Q_DIM   128

typedef __attribute__((ext_vector_type(8))) __bf16 bf16x8;
typedef __attribute__((ext_vector_type(4))) float  f32x4;

__device__ __forceinline__ ushort f2bf(float f) {
    uint32_t u = __float_as_uint(f);
    uint32_t r = (u + 0x7fffu + ((u >> 16) & 1u)) >> 16;   // RNE
    return (ushort)r;
}

__device__ __forceinline__ float bf2f(ushort u) {
    return __uint_as_float((uint32_t)u << 16);
}

// gate two fp32 lanes (exact fp32 compare, as reference) and pack to 2 bf16
// via v_cvt_pk_bf16_f32 (RNE; dst.lo = src0, dst.hi = src1 — T12 recipe).
__device__ __forceinline__ uint32_t gate_pk(float x0, float x1,
                                            float m0, float m1,
                                            float t0, float t1) {
    float a = x0 - m0, b = x1 - m1;
    float ga = (fabsf(a) >= t0) ? a : 0.f;
    float gb = (fabsf(b) >= t1) ? b : 0.f;
    uint32_t r;
    asm("v_cvt_pk_bf16_f32 %0, %1, %2" : "=v"(r) : "v"(ga), "v"(gb));
    return r;
}

__device__ __forceinline__ void async16(void* lds, const void* g) {
    __builtin_amdgcn_global_load_lds(
        (const __attribute__((address_space(1))) unsigned int*)g,
        (__attribute__((address_space(3))) unsigned int*)lds, 16, 0, 0);
}

// ================= pre-pass bodies ===========================================

// W [I][OUT] f32 -> WT [OUT][I] bf16, one 64x64 tile
__device__ __forceinline__ void transpose_w_block(const float* __restrict__ W,
                                                  ushort* __restrict__ WT,
                                                  int c0, int i0, int t,
                                                  float (*tile)[65]) {
    {
        int dc4 = (t & 15) * 4;
        int di  = t >> 4;
        #pragma unroll
        for (int p = 0; p < 4; ++p) {
            int ii = di + p * 16;
            float4 v = *(const float4*)(W + (size_t)(i0 + ii) * OUT_DIM + c0 + dc4);
            tile[ii][dc4 + 0] = v.x; tile[ii][dc4 + 1] = v.y;
            tile[ii][dc4 + 2] = v.z; tile[ii][dc4 + 3] = v.w;
        }
    }
    __syncthreads();
    {
        int iq = (t & 15) * 4;
        int dc = t >> 4;
        #pragma unroll
        for (int p = 0; p < 4; ++p) {
            int cc = dc + p * 16;
            ushort4 o;
            o.x = f2bf(tile[iq + 0][cc]);
            o.y = f2bf(tile[iq + 1][cc]);
            o.z = f2bf(tile[iq + 2][cc]);
            o.w = f2bf(tile[iq + 3][cc]);
            *(ushort4*)(WT + (size_t)(c0 + cc) * I_DIM + i0 + iq) = o;
        }
    }
}

// th [I][N] f32 -> thT [N][I] f32, one 64(i) x 32(n) tile via LDS
__device__ __forceinline__ void transpose_th_block(const float* __restrict__ th,
                                                   float* __restrict__ thT,
                                                   int i0, int t, float* tile) {
    {   // load: 4 threads cover one 128B row of th
        int ri = t >> 2;                 // 0..63
        int nc = (t & 3) * 8;
        float4 v0 = *(const float4*)(th + (size_t)(i0 + ri) * N_STR + nc);
        float4 v1 = *(const float4*)(th + (size_t)(i0 + ri) * N_STR + nc + 4);
        tile[ri * 33 + nc + 0] = v0.x; tile[ri * 33 + nc + 1] = v0.y;
        tile[ri * 33 + nc + 2] = v0.z; tile[ri * 33 + nc + 3] = v0.w;
        tile[ri * 33 + nc + 4] = v1.x; tile[ri * 33 + nc + 5] = v1.y;
        tile[ri * 33 + nc + 6] = v1.z; tile[ri * 33 + nc + 7] = v1.w;
    }
    __syncthreads();
    {   // store: thread -> (n, 8 consecutive i)
        int n  = t >> 3;                 // 0..31
        int di = (t & 7) * 8;
        float4 o0, o1;
        o0.x = tile[(di + 0) * 33 + n]; o0.y = tile[(di + 1) * 33 + n];
        o0.z = tile[(di + 2) * 33 + n]; o0.w = tile[(di + 3) * 33 + n];
        o1.x = tile[(di + 4) * 33 + n]; o1.y = tile[(di + 5) * 33 + n];
        o1.z = tile[(di + 6) * 33 + n]; o1.w = tile[(di + 7) * 33 + n];
        *(float4*)(thT + (size_t)n * I_DIM + i0 + di) = o0;
        *(float4*)(thT + (size_t)n * I_DIM + i0 + di + 4) = o1;
    }
}

// ---------------- merged pre-pass: th-transpose (0..63) + W-transpose --------
__global__ __launch_bounds__(256) void k_prep7(const float* __restrict__ W,
                                               ushort* __restrict__ WT,
                                               const float* __restrict__ th,
                                               float* __restrict__ thT) {
    __shared__ __align__(16) float smem[64 * 65];   // 16.25 KB, reused
    int b = blockIdx.x;
    int t = threadIdx.x;
    if (b < 64) {
        transpose_th_block(th, thT, b * 64, t, smem);
    } else {
        int tb = b - 64;                // 0..4095
        transpose_w_block(W, WT, (tb & 63) * 64, (tb >> 6) * 64, t,
                          (float (*)[65])smem);
    }
}

// ---------------- main v10: inline gate from fp32 x (XB/MB eliminated) -------
// tile 128x128, 4 waves of 64x64, BK=64. sA single (16K) + sB dbuf (32K)
// = 48 KB -> 3 blocks/CU. Split-K=3 uneven: 22/21/21 steps of BK=64.
// A-staging: read x fp32 + thT/mu vectors, gate exactly in fp32 (same as
// reference), cvt_pk to bf16, write swizzled sA. Transform sits between the
// two barriers, off the prefetched critical path.

__global__ __launch_bounds__(256, 3) void k_main10(const float* __restrict__ x,
                                                   const ushort* __restrict__ WT,
                                                   const float* __restrict__ thT,
                                                   const float* __restrict__ mu,
                                                   ushort* __restrict__ PB0,
                                                   ushort* __restrict__ PB1,
                                                   ushort* __restrict__ PB2) {
    __shared__ ushort sA[128 * 64];      // 16 KB (single)
    __shared__ ushort sB[2][128 * 64];   // 16 KB each

    int bid  = blockIdx.x;               // 0..767
    int xcd  = bid & 7;
    int slot = bid >> 3;                 // 0..95
    int n    = xcd * 4 + (slot & 3);     // stripe (XCD-local group of 4)
    int rt   = (slot >> 2) & 7;          // row tile 0..7
    int kq   = slot >> 5;                // 0..2
    int r0   = rt * 128;
    int k0   = (kq == 0) ? 0 : (kq == 1) ? 1408 : 2752;
    int NT   = (kq == 0) ? 22 : 21;
    int cbase = n * Q_DIM;
    ushort* P = (kq == 0) ? PB0 : (kq == 1) ? PB1 : PB2;

    int tid  = threadIdx.x;
    int lane = tid & 63;
    int wave = tid >> 6;                 // 0..3
    int wr   = wave >> 1;                // 0..1 : 64-row group
    int wc   = wave & 1;                 // 0..1 : 64-col group
    int lrow = lane & 15;
    int lgrp = lane >> 4;

    // ---- A staging maps: pass p: row = p*32 + (tid>>3), 8 consecutive k
    const float* pX[4];
    int awz[4];
    const int ak = (tid & 7) * 8;        // k elem offset 0..56
    {
        int ar = tid >> 3;
        #pragma unroll
        for (int p = 0; p < 4; ++p) {
            int row = p * 32 + ar;
            pX[p] = x + (size_t)(r0 + row) * I_DIM + k0 + ak;
            awz[p] = row * 128 + ((ak * 2) ^ ((row & 7) << 4));
        }
    }
    const float* pTH = thT + (size_t)n * I_DIM + k0 + ak;
    const float* pMU = mu + k0 + ak;

    // ---- B staging maps: 16 chunks of 1KB; pre-swizzled source
    const char* pBq[4];
    int ldsBo[4];
    #pragma unroll
    for (int q = 0; q < 4; ++q) {
        int chunk = wave * 4 + q;
        int col = chunk * 8 + (lane >> 3);
        pBq[q] = (const char*)WT + (size_t)(cbase + col) * (I_DIM * 2)
               + (size_t)k0 * 2 + (((lane & 7) ^ (lane >> 3)) << 4);
        ldsBo[q] = chunk * 1024;
    }

    f32x4 acc[4][4];
    #pragma unroll
    for (int m2 = 0; m2 < 4; ++m2)
        #pragma unroll
        for (int nn = 0; nn < 4; ++nn)
            acc[m2][nn] = (f32x4){0.f, 0.f, 0.f, 0.f};

    float4 xa[4][2], thv[2], muv[2];     // held A data (next tile)

    // ---- prologue: A(0) regs; B0 DMA; gate+write sA(0); A(1) regs; barrier
    #pragma unroll
    for (int p = 0; p < 4; ++p) {
        xa[p][0] = *(const float4*)pX[p];
        xa[p][1] = *((const float4*)pX[p] + 1);
    }
    thv[0] = *(const float4*)pTH; thv[1] = *((const float4*)pTH + 1);
    muv[0] = *(const float4*)pMU; muv[1] = *((const float4*)pMU + 1);
    #pragma unroll
    for (int q = 0; q < 4; ++q) async16((char*)sB[0] + ldsBo[q], pBq[q]);
    #pragma unroll
    for (int p = 0; p < 4; ++p) {
        uint4 z;
        z.x = gate_pk(xa[p][0].x, xa[p][0].y, muv[0].x, muv[0].y, thv[0].x, thv[0].y);
        z.y = gate_pk(xa[p][0].z, xa[p][0].w, muv[0].z, muv[0].w, thv[0].z, thv[0].w);
        z.z = gate_pk(xa[p][1].x, xa[p][1].y, muv[1].x, muv[1].y, thv[1].x, thv[1].y);
        z.w = gate_pk(xa[p][1].z, xa[p][1].w, muv[1].z, muv[1].w, thv[1].z, thv[1].w);
        *(uint4*)((char*)sA + awz[p]) = z;
    }
    #pragma unroll
    for (int p = 0; p < 4; ++p) {
        xa[p][0] = *(const float4*)(pX[p] + 64);
        xa[p][1] = *((const float4*)(pX[p] + 64) + 1);
    }
    thv[0] = *(const float4*)(pTH + 64); thv[1] = *((const float4*)(pTH + 64) + 1);
    muv[0] = *(const float4*)(pMU + 64); muv[1] = *((const float4*)(pMU + 64) + 1);
    __syncthreads();                     // sA(0), sB[0] ready

    for (int t = 0; t < NT; ++t) {
        // issue B(t+1) DMA into the other sB buffer (lands under compute)
        if (t + 1 < NT) {
            #pragma unroll
            for (int q = 0; q < 4; ++q)
                async16((char*)sB[(t + 1) & 1] + ldsBo[q],
                        pBq[q] + (size_t)(t + 1) * 128);
        }
        // ---- compute tile t (sA single, sB[t&1])
        const char* sAc = (const char*)sA;
        const char* sBc = (const char*)sB[t & 1];
        __builtin_amdgcn_s_setprio(1);
        #pragma unroll
        for (int ks = 0; ks < 2; ++ks) {
            int kb = ks * 64 + (lgrp << 4);
            bf16x8 af[4], bfr[4];
            #pragma unroll
            for (int m2 = 0; m2 < 4; ++m2) {
                int row = wr * 64 + m2 * 16 + lrow;
                af[m2] = *(const bf16x8*)(sAc + row * 128 + (kb ^ ((row & 7) << 4)));
            }
            #pragma unroll
            for (int nn = 0; nn < 4; ++nn) {
                int col = wc * 64 + nn * 16 + lrow;
                bfr[nn] = *(const bf16x8*)(sBc + col * 128 + (kb ^ ((col & 7) << 4)));
            }
            #pragma unroll
            for (int m2 = 0; m2 < 4; ++m2)
                #pragma unroll
                for (int nn = 0; nn < 4; ++nn)
                    acc[m2][nn] = __builtin_amdgcn_mfma_f32_16x16x32_bf16(af[m2], bfr[nn], acc[m2][nn], 0, 0, 0);
        }
        __builtin_amdgcn_s_setprio(0);
        __syncthreads();                 // compute done; B(t+1)+A-regs drained
        // ---- gate+write sA(t+1); prefetch A(t+2) regs
        if (t + 1 < NT) {
            #pragma unroll
            for (int p = 0; p < 4; ++p) {
                uint4 z;
                z.x = gate_pk(xa[p][0].x, xa[p][0].y, muv[0].x, muv[0].y, thv[0].x, thv[0].y);
                z.y = gate_pk(xa[p][0].z, xa[p][0].w, muv[0].z, muv[0].w, thv[0].z, thv[0].w);
                z.z = gate_pk(xa[p][1].x, xa[p][1].y, muv[1].x, muv[1].y, thv[1].x, thv[1].y);
                z.w = gate_pk(xa[p][1].z, xa[p][1].w, muv[1].z, muv[1].w, thv[1].z, thv[1].w);
                *(uint4*)((char*)sA + awz[p]) = z;
            }
            if (t + 2 < NT) {
                int off = (t + 2) * 64;
                #pragma unroll
                for (int p = 0; p < 4; ++p) {
                    xa[p][0] = *(const float4*)(pX[p] + off);
                    xa[p][1] = *((const float4*)(pX[p] + off) + 1);
                }
                thv[0] = *(const float4*)(pTH + off);
                thv[1] = *((const float4*)(pTH + off) + 1);
                muv[0] = *(const float4*)(pMU + off);
                muv[1] = *((const float4*)(pMU + off) + 1);
            }
        }
        __syncthreads();                 // sA(t+1) visible
    }

    // ---- epilogue: bf16 partials (summed + out_mu added in k_reduce3b)
    #pragma unroll
    for (int nn = 0; nn < 4; ++nn) {
        int col = cbase + wc * 64 + nn * 16 + lrow;
        #pragma unroll
        for (int m2 = 0; m2 < 4; ++m2) {
            int rbase = r0 + wr * 64 + m2 * 16 + lgrp * 4;
            #pragma unroll
            for (int j = 0; j < 4; ++j)
                P[(size_t)(rbase + j) * OUT_DIM + col] = f2bf(acc[m2][nn][j]);
        }
    }
}

// ---------------- reduce: out = PB0 + PB1 + PB2 + out_mu (bf16 partials) -----
__global__ __launch_bounds__(256) void k_reduce3b(float* __restrict__ out,
                                                  const ushort* __restrict__ PB0,
                                                  const ushort* __restrict__ PB1,
                                                  const ushort* __restrict__ PB2,
                                                  const float* __restrict__ out_mu) {
    int idx = blockIdx.x * 256 + threadIdx.x;       // 8-elem group, 524288 total
    uint4 a = *(const uint4*)(PB0 + (size_t)idx * 8);
    uint4 b = *(const uint4*)(PB1 + (size_t)idx * 8);
    uint4 c = *(const uint4*)(PB2 + (size_t)idx * 8);
    const float* om = out_mu + (idx & 511) * 8;
    float4 m0 = *(const float4*)om;
    float4 m1 = *(const float4*)(om + 4);
    float4 o0, o1;
    o0.x = bf2f((ushort)(a.x & 0xFFFF)) + bf2f((ushort)(b.x & 0xFFFF)) + bf2f((ushort)(c.x & 0xFFFF)) + m0.x;
    o0.y = bf2f((ushort)(a.x >> 16))    + bf2f((ushort)(b.x >> 16))    + bf2f((ushort)(c.x >> 16))    + m0.y;
    o0.z = bf2f((ushort)(a.y & 0xFFFF)) + bf2f((ushort)(b.y & 0xFFFF)) + bf2f((ushort)(c.y & 0xFFFF)) + m0.z;
    o0.w = bf2f((ushort)(a.y >> 16))    + bf2f((ushort)(b.y >> 16))    + bf2f((ushort)(c.y >> 16))    + m0.w;
    o1.x = bf2f((ushort)(a.z & 0xFFFF)) + bf2f((ushort)(b.z & 0xFFFF)) + bf2f((ushort)(c.z & 0xFFFF)) + m1.x;
    o1.y = bf2f((ushort)(a.z >> 16))    + bf2f((ushort)(b.z >> 16))    + bf2f((ushort)(c.z >> 16))    + m1.y;
    o1.z = bf2f((ushort)(a.w & 0xFFFF)) + bf2f((ushort)(b.w & 0xFFFF)) + bf2f((ushort)(c.w & 0xFFFF)) + m1.z;
    o1.w = bf2f((ushort)(a.w >> 16))    + bf2f((ushort)(b.w >> 16))    + bf2f((ushort)(c.w >> 16))    + m1.w;
    float* dst = out + (size_t)idx * 8;
    *(float4*)dst = o0;
    *(float4*)(dst + 4) = o1;
}

// ---------------- fallback: naive fp32 ---------------------------------------
__global__ __launch_bounds__(256) void k_naive(const float* __restrict__ x,
                                               const float* __restrict__ W,
                                               const float* __restrict__ th,
                                               const float* __restrict__ mu,
                                               const float* __restrict__ out_mu,
                                               float* __restrict__ out) {
    int idx = blockIdx.x * 256 + threadIdx.x;
    int r = idx >> 12;
    int c = idx & 4095;
    int n = c >> 7;
    float s = 0.f;
    for (int i = 0; i < I_DIM; ++i) {
        float xo = x[(size_t)r * I_DIM + i] - mu[i];
        if (fabsf(xo) >= th[i * N_STR + n])
            s += xo * W[(size_t)i * OUT_DIM + c];
    }
    out[idx] = s + out_mu[c];
}

extern "C" void kernel_launch(void* const* d_in, const int* in_sizes, int n_in,
                              void* d_out, int out_size, void* d_ws, size_t ws_size,
                              hipStream_t stream) {
    const float* x      = (const float*)d_in[0];
    const float* W      = (const float*)d_in[1];
    const float* th     = (const float*)d_in[2];
    const float* mu     = (const float*)d_in[3];
    const float* out_mu = (const float*)d_in[4];
    float* out = (float*)d_out;

    const size_t wT_b  = (size_t)OUT_DIM * I_DIM * sizeof(ushort);   // 32 MiB
    const size_t thT_b = (size_t)N_STR * I_DIM * sizeof(float);      // 0.5 MiB
    const size_t pb_b  = (size_t)R_TOTAL * OUT_DIM * sizeof(ushort); // 8 MiB each

    ushort* WT  = (ushort*)d_ws;
    float*  thT = (float*)((char*)d_ws + wT_b);
    ushort* PB0 = (ushort*)((char*)d_ws + wT_b + thT_b);
    ushort* PB1 = (ushort*)((char*)d_ws + wT_b + thT_b + pb_b);
    ushort* PB2 = (ushort*)((char*)d_ws + wT_b + thT_b + 2 * pb_b);

    if (ws_size >= wT_b + thT_b + 3 * pb_b) {
        k_prep7<<<64 + 4096, 256, 0, stream>>>(W, WT, th, thT);
        k_main10<<<768, 256, 0, stream>>>(x, WT, thT, mu, PB0, PB1, PB2);
        k_reduce3b<<<(R_TOTAL * OUT_DIM / 8) / 256, 256, 0, stream>>>(out, PB0, PB1, PB2, out_mu);
    } else {
        k_naive<<<(R_TOTAL * OUT_DIM) / 256, 256, 0, stream>>>(x, W, th, mu, out_mu, out);
    }
}